// Round 1
// baseline (713.086 us; speedup 1.0000x reference)
//
#include <hip/hip_runtime.h>
#include <hip/hip_bf16.h>

// Net: deform-conv MNIST. B=2048.
// K1: x(B,1,28,28) --offset conv(1->2,3x3,p1)+remap+bilinear--> d1(B,1,28,28)
// K2: conv 5x5 p2 (1->16) + relu + maxpool2 -> h1(B,16,14,14)
// K3: offset conv(16->32,3x3,p1)+remap+bilinear -> d2(B,16,14,14)
// K4: conv 5x5 p2 (16->32) + relu + maxpool2 -> h2(B,32,7,7)
// K5: FC 1568->10 -> out(B,10)

#define B_IMG 2048

__global__ __launch_bounds__(256) void k_deform1(const float* __restrict__ x,
                                                 const float* __restrict__ w_off,  // (2,1,3,3)
                                                 float* __restrict__ d1) {
    __shared__ float xs[784];
    __shared__ float wo[18];
    int b = blockIdx.x;
    const float* xi = x + b * 784;
    for (int i = threadIdx.x; i < 784; i += 256) xs[i] = xi[i];
    if (threadIdx.x < 18) wo[threadIdx.x] = w_off[threadIdx.x];
    __syncthreads();
    for (int p = threadIdx.x; p < 784; p += 256) {
        int h = p / 28, w = p % 28;
        float off[2];
        int flat0 = h * 56 + w * 2;
#pragma unroll
        for (int k = 0; k < 2; ++k) {
            int flat = flat0 + k;
            int c = flat / 784;
            int r = flat % 784;
            int hh = r / 28, ww = r % 28;
            float s = 0.f;
#pragma unroll
            for (int dy = 0; dy < 3; ++dy) {
                int yy = hh + dy - 1;
                if (yy < 0 || yy >= 28) continue;
#pragma unroll
                for (int dx = 0; dx < 3; ++dx) {
                    int xx = ww + dx - 1;
                    if (xx >= 0 && xx < 28)
                        s += wo[c * 9 + dy * 3 + dx] * xs[yy * 28 + xx];
                }
            }
            off[k] = s;
        }
        float cy = fminf(fmaxf((float)h + off[0], 0.f), 27.f);
        float cx = fminf(fmaxf((float)w + off[1], 0.f), 27.f);
        float y0f = floorf(cy), x0f = floorf(cx);
        int y0 = (int)y0f, x0 = (int)x0f;
        int y1 = (int)ceilf(cy), x1 = (int)ceilf(cx);
        float ty = cy - y0f, tx = cx - x0f;
        float vlt = xs[y0 * 28 + x0], vrt = xs[y0 * 28 + x1];
        float vlb = xs[y1 * 28 + x0], vrb = xs[y1 * 28 + x1];
        float vt = vlt + (vrt - vlt) * tx;
        float vb = vlb + (vrb - vlb) * tx;
        d1[b * 784 + p] = vt + (vb - vt) * ty;
    }
}

__global__ __launch_bounds__(256) void k_conv1(const float* __restrict__ d1,
                                               const float* __restrict__ w,     // (16,1,5,5)
                                               const float* __restrict__ bias,  // (16)
                                               float* __restrict__ h1) {        // (B,16,14,14)
    __shared__ float img[784];
    __shared__ float ws[400];
    __shared__ float bs[16];
    int b = blockIdx.x;
    for (int i = threadIdx.x; i < 784; i += 256) img[i] = d1[b * 784 + i];
    for (int i = threadIdx.x; i < 400; i += 256) ws[i] = w[i];
    if (threadIdx.x < 16) bs[threadIdx.x] = bias[threadIdx.x];
    __syncthreads();
    for (int o = threadIdx.x; o < 16 * 196; o += 256) {
        int oc = o / 196;
        int r = o % 196;
        int i = r / 14, j = r % 14;
        float bv = bs[oc];
        float m = 0.f;  // relu then max => max(conv vals, 0)
#pragma unroll
        for (int py = 0; py < 2; ++py)
#pragma unroll
            for (int px = 0; px < 2; ++px) {
                int y = 2 * i + py, xp = 2 * j + px;
                float s = bv;
#pragma unroll
                for (int dy = 0; dy < 5; ++dy) {
                    int yy = y + dy - 2;
                    if (yy < 0 || yy >= 28) continue;
#pragma unroll
                    for (int dx = 0; dx < 5; ++dx) {
                        int xx = xp + dx - 2;
                        if (xx >= 0 && xx < 28)
                            s += ws[oc * 25 + dy * 5 + dx] * img[yy * 28 + xx];
                    }
                }
                m = fmaxf(m, s);
            }
        h1[(b * 16 + oc) * 196 + r] = m;
    }
}

__global__ __launch_bounds__(256) void k_deform2(const float* __restrict__ h1,  // (B,16,14,14)
                                                 const float* __restrict__ w2,  // (32,16,3,3)
                                                 float* __restrict__ d2) {
    __shared__ float img[3136];  // 16*196
    __shared__ float ws[4608];   // 32*16*9
    int b = blockIdx.x;
    for (int i = threadIdx.x; i < 3136; i += 256) img[i] = h1[b * 3136 + i];
    for (int i = threadIdx.x; i < 4608; i += 256) ws[i] = w2[i];
    __syncthreads();
    for (int o = threadIdx.x; o < 3136; o += 256) {
        int c = o / 196;
        int r = o % 196;
        int h = r / 14, w = r % 14;
        float off[2];
        int flat0 = c * 392 + h * 28 + w * 2;
#pragma unroll
        for (int k = 0; k < 2; ++k) {
            int flat = flat0 + k;
            int cp = flat / 196;
            int rr = flat % 196;
            int hh = rr / 14, ww = rr % 14;
            float s = 0.f;
            for (int ic = 0; ic < 16; ++ic) {
#pragma unroll
                for (int dy = 0; dy < 3; ++dy) {
                    int yy = hh + dy - 1;
                    if (yy < 0 || yy >= 14) continue;
#pragma unroll
                    for (int dx = 0; dx < 3; ++dx) {
                        int xx = ww + dx - 1;
                        if (xx >= 0 && xx < 14)
                            s += ws[(cp * 16 + ic) * 9 + dy * 3 + dx] * img[ic * 196 + yy * 14 + xx];
                    }
                }
            }
            off[k] = s;
        }
        float cy = fminf(fmaxf((float)h + off[0], 0.f), 13.f);
        float cx = fminf(fmaxf((float)w + off[1], 0.f), 13.f);
        float y0f = floorf(cy), x0f = floorf(cx);
        int y0 = (int)y0f, x0 = (int)x0f;
        int y1 = (int)ceilf(cy), x1 = (int)ceilf(cx);
        float ty = cy - y0f, tx = cx - x0f;
        const float* ch = img + c * 196;
        float vlt = ch[y0 * 14 + x0], vrt = ch[y0 * 14 + x1];
        float vlb = ch[y1 * 14 + x0], vrb = ch[y1 * 14 + x1];
        float vt = vlt + (vrt - vlt) * tx;
        float vb = vlb + (vrb - vlb) * tx;
        d2[b * 3136 + o] = vt + (vb - vt) * ty;
    }
}

__global__ __launch_bounds__(256) void k_conv2(const float* __restrict__ d2,    // (B,16,14,14)
                                               const float* __restrict__ w,     // (32,16,5,5)
                                               const float* __restrict__ bias,  // (32)
                                               float* __restrict__ h2) {        // (B,32,7,7)
    __shared__ float img[3136];
    __shared__ float ws[12800];  // [oc][ic][5][5]
    __shared__ float bs[32];
    int b = blockIdx.x;
    for (int i = threadIdx.x; i < 3136; i += 256) img[i] = d2[b * 3136 + i];
    for (int i = threadIdx.x; i < 12800; i += 256) ws[i] = w[i];
    if (threadIdx.x < 32) bs[threadIdx.x] = bias[threadIdx.x];
    __syncthreads();
    int t = threadIdx.x;
    if (t < 196) {
        int pos = t % 49;   // pooled spatial
        int ocg = t / 49;   // 0..3 -> oc = ocg*8 .. +8
        int i = pos / 7, j = pos % 7;
        float acc[8][4];
#pragma unroll
        for (int a = 0; a < 8; ++a)
#pragma unroll
            for (int q = 0; q < 4; ++q) acc[a][q] = 0.f;
        int y0 = 2 * i - 2, x0 = 2 * j - 2;
        for (int ic = 0; ic < 16; ++ic) {
            float patch[6][6];
#pragma unroll
            for (int r = 0; r < 6; ++r) {
                int yy = y0 + r;
#pragma unroll
                for (int cc = 0; cc < 6; ++cc) {
                    int xx = x0 + cc;
                    patch[r][cc] = (yy >= 0 && yy < 14 && xx >= 0 && xx < 14)
                                       ? img[ic * 196 + yy * 14 + xx]
                                       : 0.f;
                }
            }
#pragma unroll
            for (int oo = 0; oo < 8; ++oo) {
                const float* wp = &ws[((ocg * 8 + oo) * 16 + ic) * 25];
#pragma unroll
                for (int dy = 0; dy < 5; ++dy)
#pragma unroll
                    for (int dx = 0; dx < 5; ++dx) {
                        float wv = wp[dy * 5 + dx];
                        acc[oo][0] += wv * patch[dy][dx];
                        acc[oo][1] += wv * patch[dy][dx + 1];
                        acc[oo][2] += wv * patch[dy + 1][dx];
                        acc[oo][3] += wv * patch[dy + 1][dx + 1];
                    }
            }
        }
#pragma unroll
        for (int oo = 0; oo < 8; ++oo) {
            int oc = ocg * 8 + oo;
            float bv = bs[oc];
            float m = fmaxf(
                fmaxf(fmaxf(acc[oo][0] + bv, acc[oo][1] + bv), fmaxf(acc[oo][2] + bv, acc[oo][3] + bv)),
                0.f);
            h2[(b * 32 + oc) * 49 + pos] = m;
        }
    }
}

__global__ __launch_bounds__(64) void k_fc(const float* __restrict__ h2,  // (B,1568)
                                           const float* __restrict__ fw,  // (10,1568)
                                           const float* __restrict__ fb,  // (10)
                                           float* __restrict__ out) {     // (B,10)
    int b = blockIdx.x;
    int lane = threadIdx.x;
    float acc[10];
#pragma unroll
    for (int o = 0; o < 10; ++o) acc[o] = 0.f;
    const float* row = h2 + b * 1568;
    for (int k = lane; k < 1568; k += 64) {
        float v = row[k];
#pragma unroll
        for (int o = 0; o < 10; ++o) acc[o] += v * fw[o * 1568 + k];
    }
#pragma unroll
    for (int o = 0; o < 10; ++o) {
        float s = acc[o];
#pragma unroll
        for (int m = 32; m > 0; m >>= 1) s += __shfl_xor(s, m);
        if (lane == 0) out[b * 10 + o] = s + fb[o];
    }
}

extern "C" void kernel_launch(void* const* d_in, const int* in_sizes, int n_in,
                              void* d_out, int out_size, void* d_ws, size_t ws_size,
                              hipStream_t stream) {
    const float* x       = (const float*)d_in[0];
    const float* off1_w  = (const float*)d_in[1];
    const float* conv1_w = (const float*)d_in[2];
    const float* conv1_b = (const float*)d_in[3];
    const float* off2_w  = (const float*)d_in[4];
    const float* conv2_w = (const float*)d_in[5];
    const float* conv2_b = (const float*)d_in[6];
    const float* fc_w    = (const float*)d_in[7];
    const float* fc_b    = (const float*)d_in[8];
    float* out = (float*)d_out;

    char* ws = (char*)d_ws;
    // region R1: d1 (B*784) then reused as d2 (B*3136) -> size max = B*3136*4
    // region R2: h1 (B*3136*4)
    // region R3: h2 (B*32*49*4)
    size_t R1 = 0;
    size_t R2 = R1 + (size_t)B_IMG * 3136 * 4;
    size_t R3 = R2 + (size_t)B_IMG * 3136 * 4;
    float* d1 = (float*)(ws + R1);
    float* h1 = (float*)(ws + R2);
    float* d2 = (float*)(ws + R1);  // reuse R1 (d1 dead after k_conv1)
    float* h2 = (float*)(ws + R3);

    k_deform1<<<B_IMG, 256, 0, stream>>>(x, off1_w, d1);
    k_conv1<<<B_IMG, 256, 0, stream>>>(d1, conv1_w, conv1_b, h1);
    k_deform2<<<B_IMG, 256, 0, stream>>>(h1, off2_w, d2);
    k_conv2<<<B_IMG, 256, 0, stream>>>(d2, conv2_w, conv2_b, h2);
    k_fc<<<B_IMG, 64, 0, stream>>>(h2, fc_w, fc_b, out);
}

// Round 2
// 418.712 us; speedup vs baseline: 1.7030x; 1.7030x over previous
//
#include <hip/hip_runtime.h>
#include <hip/hip_bf16.h>

// Net: deform-conv MNIST. B=2048. All fp32 VALU compute.
// K1: deform1 (offset conv 1->2 3x3 p1 + remap + bilinear), padded LDS image
// K2: conv1 5x5 p2 (1->16) + relu + pool, padded image, patch-in-regs
// K3: deform2: phase A = offset conv (32,14,14) into LDS (branch-free,
//     reg-blocked 2oc x 14col), phase B = direct remap + bilinear
// K4: conv2 5x5 p2 (16->32) + relu + pool, padded image, 448 thr
// K5: FC 1568->10

#define B_IMG 2048

__global__ __launch_bounds__(256) void k_deform1(const float* __restrict__ x,
                                                 const float* __restrict__ w_off,  // (2,1,3,3)
                                                 float* __restrict__ d1) {
    __shared__ float xs[900];  // [30][30] padded by 1
    __shared__ float wo[18];
    int b = blockIdx.x;
    const float* xi = x + b * 784;
    for (int i = threadIdx.x; i < 900; i += 256) xs[i] = 0.f;
    if (threadIdx.x < 18) wo[threadIdx.x] = w_off[threadIdx.x];
    __syncthreads();
    for (int i = threadIdx.x; i < 784; i += 256)
        xs[(i / 28 + 1) * 30 + (i % 28) + 1] = xi[i];
    __syncthreads();
    for (int p = threadIdx.x; p < 784; p += 256) {
        int h = p / 28, w = p % 28;
        float off[2];
        int flat0 = h * 56 + w * 2;
#pragma unroll
        for (int k = 0; k < 2; ++k) {
            int flat = flat0 + k;
            int c = flat / 784;
            int r = flat % 784;
            int hh = r / 28, ww = r % 28;
            float s = 0.f;
#pragma unroll
            for (int dy = 0; dy < 3; ++dy)
#pragma unroll
                for (int dx = 0; dx < 3; ++dx)
                    s += wo[c * 9 + dy * 3 + dx] * xs[(hh + dy) * 30 + ww + dx];
            off[k] = s;
        }
        float cy = fminf(fmaxf((float)h + off[0], 0.f), 27.f);
        float cx = fminf(fmaxf((float)w + off[1], 0.f), 27.f);
        float y0f = floorf(cy), x0f = floorf(cx);
        int y0 = (int)y0f, x0 = (int)x0f;
        int y1 = (int)ceilf(cy), x1 = (int)ceilf(cx);
        float ty = cy - y0f, tx = cx - x0f;
        float vlt = xs[(y0 + 1) * 30 + x0 + 1], vrt = xs[(y0 + 1) * 30 + x1 + 1];
        float vlb = xs[(y1 + 1) * 30 + x0 + 1], vrb = xs[(y1 + 1) * 30 + x1 + 1];
        float vt = vlt + (vrt - vlt) * tx;
        float vb = vlb + (vrb - vlb) * tx;
        d1[b * 784 + p] = vt + (vb - vt) * ty;
    }
}

__global__ __launch_bounds__(256) void k_conv1(const float* __restrict__ d1,
                                               const float* __restrict__ w,     // (16,1,5,5)
                                               const float* __restrict__ bias,  // (16)
                                               float* __restrict__ h1) {        // (B,16,14,14)
    __shared__ float img2[1024];  // [32][32], pad 2
    __shared__ float ws[400];
    __shared__ float bs[16];
    int b = blockIdx.x;
    for (int i = threadIdx.x; i < 1024; i += 256) img2[i] = 0.f;
    for (int i = threadIdx.x; i < 400; i += 256) ws[i] = w[i];
    if (threadIdx.x < 16) bs[threadIdx.x] = bias[threadIdx.x];
    __syncthreads();
    for (int i = threadIdx.x; i < 784; i += 256)
        img2[(i / 28 + 2) * 32 + (i % 28) + 2] = d1[b * 784 + i];
    __syncthreads();
    for (int o = threadIdx.x; o < 16 * 196; o += 256) {
        int oc = o / 196;
        int r = o % 196;
        int i = r / 14, j = r % 14;
        float wv[25];
#pragma unroll
        for (int q = 0; q < 25; ++q) wv[q] = ws[oc * 25 + q];
        float patch[6][6];
#pragma unroll
        for (int q = 0; q < 6; ++q)
#pragma unroll
            for (int cc = 0; cc < 6; ++cc)
                patch[q][cc] = img2[(2 * i + q) * 32 + 2 * j + cc];
        float bv = bs[oc];
        float m = 0.f;
#pragma unroll
        for (int py = 0; py < 2; ++py)
#pragma unroll
            for (int px = 0; px < 2; ++px) {
                float s = bv;
#pragma unroll
                for (int dy = 0; dy < 5; ++dy)
#pragma unroll
                    for (int dx = 0; dx < 5; ++dx)
                        s += wv[dy * 5 + dx] * patch[py + dy][px + dx];
                m = fmaxf(m, s);
            }
        h1[(b * 16 + oc) * 196 + r] = m;
    }
}

__global__ __launch_bounds__(256) void k_deform2(const float* __restrict__ h1,  // (B,16,14,14)
                                                 const float* __restrict__ w2,  // (32,16,3,3)
                                                 float* __restrict__ d2) {
    __shared__ float imgp[16][16][16];  // (ic, y+1, x+1) zero-padded; 16KB
    __shared__ float ws2[32 * 145];     // [oc]: 144 weights + 1 pad (bank decorrelate)
    __shared__ _Float16 offbuf[6272];   // conv output (32,14,14), fp16
    int b = blockIdx.x;
    int t = threadIdx.x;
    for (int i = t; i < 4096; i += 256) ((float*)imgp)[i] = 0.f;
    for (int i = t; i < 4608; i += 256) {
        int oc = i / 144, rem = i % 144;
        ws2[oc * 145 + rem] = w2[i];
    }
    __syncthreads();
    for (int i = t; i < 3136; i += 256) {
        int ic = i / 196, r = i % 196;
        imgp[ic][r / 14 + 1][r % 14 + 1] = h1[b * 3136 + i];
    }
    __syncthreads();

    // ---- phase A: offset conv -> offbuf. item = (ocg of 2 oc) x (row) ----
    if (t < 224) {
        int ocg = t & 15, row = t >> 4;
        int oc0 = ocg * 2, oc1 = oc0 + 1;
        float acc0[14], acc1[14];
#pragma unroll
        for (int c = 0; c < 14; ++c) { acc0[c] = 0.f; acc1[c] = 0.f; }
        for (int ic = 0; ic < 16; ++ic) {
            float rr_[3][16];
#pragma unroll
            for (int dy = 0; dy < 3; ++dy) {
                const float4* rp = reinterpret_cast<const float4*>(&imgp[ic][row + dy][0]);
#pragma unroll
                for (int q = 0; q < 4; ++q) {
                    float4 v = rp[q];
                    rr_[dy][q * 4 + 0] = v.x;
                    rr_[dy][q * 4 + 1] = v.y;
                    rr_[dy][q * 4 + 2] = v.z;
                    rr_[dy][q * 4 + 3] = v.w;
                }
            }
            float wa[9], wb[9];
            const float* wA = &ws2[oc0 * 145 + ic * 9];
            const float* wB = &ws2[oc1 * 145 + ic * 9];
#pragma unroll
            for (int q = 0; q < 9; ++q) { wa[q] = wA[q]; wb[q] = wB[q]; }
#pragma unroll
            for (int col = 0; col < 14; ++col) {
                float a0 = acc0[col], a1 = acc1[col];
#pragma unroll
                for (int dy = 0; dy < 3; ++dy)
#pragma unroll
                    for (int dx = 0; dx < 3; ++dx) {
                        float iv = rr_[dy][col + dx];
                        a0 += wa[dy * 3 + dx] * iv;
                        a1 += wb[dy * 3 + dx] * iv;
                    }
                acc0[col] = a0; acc1[col] = a1;
            }
        }
#pragma unroll
        for (int col = 0; col < 14; ++col) {
            offbuf[oc0 * 196 + row * 14 + col] = (_Float16)acc0[col];
            offbuf[oc1 * 196 + row * 14 + col] = (_Float16)acc1[col];
        }
    }
    __syncthreads();

    // ---- phase B: remap + bilinear (direct offbuf lookup) ----
    for (int o = t; o < 3136; o += 256) {
        int c = o / 196, rem = o % 196;
        int h = rem / 14, w = rem % 14;
        int flat0 = c * 392 + h * 28 + w * 2;
        float offy = (float)offbuf[flat0];
        float offx = (float)offbuf[flat0 + 1];
        float cy = fminf(fmaxf((float)h + offy, 0.f), 13.f);
        float cx = fminf(fmaxf((float)w + offx, 0.f), 13.f);
        float y0f = floorf(cy), x0f = floorf(cx);
        int y0 = (int)y0f, x0 = (int)x0f;
        int y1 = (int)ceilf(cy), x1 = (int)ceilf(cx);
        float ty = cy - y0f, tx = cx - x0f;
        const float* ch = &imgp[c][0][0];
        float vlt = ch[(y0 + 1) * 16 + x0 + 1], vrt = ch[(y0 + 1) * 16 + x1 + 1];
        float vlb = ch[(y1 + 1) * 16 + x0 + 1], vrb = ch[(y1 + 1) * 16 + x1 + 1];
        float vt = vlt + (vrt - vlt) * tx;
        float vb = vlb + (vrb - vlb) * tx;
        d2[b * 3136 + o] = vt + (vb - vt) * ty;
    }
}

__global__ __launch_bounds__(448) void k_conv2(const float* __restrict__ d2,    // (B,16,14,14)
                                               const float* __restrict__ w,     // (32,16,5,5)
                                               const float* __restrict__ bias,  // (32)
                                               float* __restrict__ h2) {        // (B,32,7,7)
    __shared__ float imgp[16][18][18];  // pad 2
    __shared__ float ws[12800];         // [oc][ic][5][5]
    __shared__ float bs[32];
    int b = blockIdx.x;
    int t = threadIdx.x;
    for (int i = t; i < 16 * 18 * 18; i += 448) ((float*)imgp)[i] = 0.f;
    for (int i = t; i < 12800; i += 448) ws[i] = w[i];
    if (t < 32) bs[t] = bias[t];
    __syncthreads();
    for (int i = t; i < 3136; i += 448) {
        int ic = i / 196, r = i % 196;
        imgp[ic][r / 14 + 2][r % 14 + 2] = d2[b * 3136 + i];
    }
    __syncthreads();
    if (t < 392) {
        int ocq = t / 49;  // 0..7 -> 4 oc each
        int pos = t % 49;
        int i = pos / 7, j = pos % 7;
        float acc[4][4];
#pragma unroll
        for (int a = 0; a < 4; ++a)
#pragma unroll
            for (int q = 0; q < 4; ++q) acc[a][q] = 0.f;
        for (int ic = 0; ic < 16; ++ic) {
            float patch[6][6];
#pragma unroll
            for (int q = 0; q < 6; ++q)
#pragma unroll
                for (int cc = 0; cc < 6; ++cc)
                    patch[q][cc] = imgp[ic][2 * i + q][2 * j + cc];
#pragma unroll
            for (int oo = 0; oo < 4; ++oo) {
                const float* wp = &ws[((ocq * 4 + oo) * 16 + ic) * 25];
                float wv[25];
#pragma unroll
                for (int q = 0; q < 25; ++q) wv[q] = wp[q];
#pragma unroll
                for (int dy = 0; dy < 5; ++dy)
#pragma unroll
                    for (int dx = 0; dx < 5; ++dx) {
                        float wvv = wv[dy * 5 + dx];
                        acc[oo][0] += wvv * patch[dy][dx];
                        acc[oo][1] += wvv * patch[dy][dx + 1];
                        acc[oo][2] += wvv * patch[dy + 1][dx];
                        acc[oo][3] += wvv * patch[dy + 1][dx + 1];
                    }
            }
        }
#pragma unroll
        for (int oo = 0; oo < 4; ++oo) {
            int oc = ocq * 4 + oo;
            float bv = bs[oc];
            float m = fmaxf(
                fmaxf(fmaxf(acc[oo][0] + bv, acc[oo][1] + bv), fmaxf(acc[oo][2] + bv, acc[oo][3] + bv)),
                0.f);
            h2[(b * 32 + oc) * 49 + pos] = m;
        }
    }
}

__global__ __launch_bounds__(64) void k_fc(const float* __restrict__ h2,  // (B,1568)
                                           const float* __restrict__ fw,  // (10,1568)
                                           const float* __restrict__ fb,  // (10)
                                           float* __restrict__ out) {     // (B,10)
    int b = blockIdx.x;
    int lane = threadIdx.x;
    float acc[10];
#pragma unroll
    for (int o = 0; o < 10; ++o) acc[o] = 0.f;
    const float* row = h2 + b * 1568;
    for (int k = lane; k < 1568; k += 64) {
        float v = row[k];
#pragma unroll
        for (int o = 0; o < 10; ++o) acc[o] += v * fw[o * 1568 + k];
    }
#pragma unroll
    for (int o = 0; o < 10; ++o) {
        float s = acc[o];
#pragma unroll
        for (int m = 32; m > 0; m >>= 1) s += __shfl_xor(s, m);
        if (lane == 0) out[b * 10 + o] = s + fb[o];
    }
}

extern "C" void kernel_launch(void* const* d_in, const int* in_sizes, int n_in,
                              void* d_out, int out_size, void* d_ws, size_t ws_size,
                              hipStream_t stream) {
    const float* x       = (const float*)d_in[0];
    const float* off1_w  = (const float*)d_in[1];
    const float* conv1_w = (const float*)d_in[2];
    const float* conv1_b = (const float*)d_in[3];
    const float* off2_w  = (const float*)d_in[4];
    const float* conv2_w = (const float*)d_in[5];
    const float* conv2_b = (const float*)d_in[6];
    const float* fc_w    = (const float*)d_in[7];
    const float* fc_b    = (const float*)d_in[8];
    float* out = (float*)d_out;

    char* ws = (char*)d_ws;
    size_t R1 = 0;
    size_t R2 = R1 + (size_t)B_IMG * 3136 * 4;
    size_t R3 = R2 + (size_t)B_IMG * 3136 * 4;
    float* d1 = (float*)(ws + R1);
    float* h1 = (float*)(ws + R2);
    float* d2 = (float*)(ws + R1);  // reuse R1 (d1 dead after k_conv1)
    float* h2 = (float*)(ws + R3);

    k_deform1<<<B_IMG, 256, 0, stream>>>(x, off1_w, d1);
    k_conv1<<<B_IMG, 256, 0, stream>>>(d1, conv1_w, conv1_b, h1);
    k_deform2<<<B_IMG, 256, 0, stream>>>(h1, off2_w, d2);
    k_conv2<<<B_IMG, 448, 0, stream>>>(d2, conv2_w, conv2_b, h2);
    k_fc<<<B_IMG, 64, 0, stream>>>(h2, fc_w, fc_b, out);
}

// Round 3
// 169.314 us; speedup vs baseline: 4.2116x; 2.4730x over previous
//
#include <hip/hip_runtime.h>
#include <hip/hip_bf16.h>

// Net: deform-conv MNIST. B=2048.
// K1: deform1 (fp32 VALU)
// K2: conv1 5x5 (fp32 VALU)
// K3: deform2 (fp32 VALU, LDS offset-conv + direct remap)
// K4: conv2 5x5 -> bf16 MFMA shift-GEMM (16x16x32), fused relu+pool
// K5: FC 1568->10
// prep: conv2 weights fp32 OIHW -> bf16 [spair13][oc32][k32] in ws

#define B_IMG 2048

typedef short bf16x8 __attribute__((ext_vector_type(8)));
typedef float f32x4 __attribute__((ext_vector_type(4)));

__global__ __launch_bounds__(256) void k_deform1(const float* __restrict__ x,
                                                 const float* __restrict__ w_off,  // (2,1,3,3)
                                                 float* __restrict__ d1) {
    __shared__ float xs[900];  // [30][30] padded by 1
    __shared__ float wo[18];
    int b = blockIdx.x;
    const float* xi = x + b * 784;
    for (int i = threadIdx.x; i < 900; i += 256) xs[i] = 0.f;
    if (threadIdx.x < 18) wo[threadIdx.x] = w_off[threadIdx.x];
    __syncthreads();
    for (int i = threadIdx.x; i < 784; i += 256)
        xs[(i / 28 + 1) * 30 + (i % 28) + 1] = xi[i];
    __syncthreads();
    for (int p = threadIdx.x; p < 784; p += 256) {
        int h = p / 28, w = p % 28;
        float off[2];
        int flat0 = h * 56 + w * 2;
#pragma unroll
        for (int k = 0; k < 2; ++k) {
            int flat = flat0 + k;
            int c = flat / 784;
            int r = flat % 784;
            int hh = r / 28, ww = r % 28;
            float s = 0.f;
#pragma unroll
            for (int dy = 0; dy < 3; ++dy)
#pragma unroll
                for (int dx = 0; dx < 3; ++dx)
                    s += wo[c * 9 + dy * 3 + dx] * xs[(hh + dy) * 30 + ww + dx];
            off[k] = s;
        }
        float cy = fminf(fmaxf((float)h + off[0], 0.f), 27.f);
        float cx = fminf(fmaxf((float)w + off[1], 0.f), 27.f);
        float y0f = floorf(cy), x0f = floorf(cx);
        int y0 = (int)y0f, x0 = (int)x0f;
        int y1 = (int)ceilf(cy), x1 = (int)ceilf(cx);
        float ty = cy - y0f, tx = cx - x0f;
        float vlt = xs[(y0 + 1) * 30 + x0 + 1], vrt = xs[(y0 + 1) * 30 + x1 + 1];
        float vlb = xs[(y1 + 1) * 30 + x0 + 1], vrb = xs[(y1 + 1) * 30 + x1 + 1];
        float vt = vlt + (vrt - vlt) * tx;
        float vb = vlb + (vrb - vlb) * tx;
        d1[b * 784 + p] = vt + (vb - vt) * ty;
    }
}

__global__ __launch_bounds__(256) void k_conv1(const float* __restrict__ d1,
                                               const float* __restrict__ w,     // (16,1,5,5)
                                               const float* __restrict__ bias,  // (16)
                                               float* __restrict__ h1) {        // (B,16,14,14)
    __shared__ float img2[1024];  // [32][32], pad 2
    __shared__ float ws[400];
    __shared__ float bs[16];
    int b = blockIdx.x;
    for (int i = threadIdx.x; i < 1024; i += 256) img2[i] = 0.f;
    for (int i = threadIdx.x; i < 400; i += 256) ws[i] = w[i];
    if (threadIdx.x < 16) bs[threadIdx.x] = bias[threadIdx.x];
    __syncthreads();
    for (int i = threadIdx.x; i < 784; i += 256)
        img2[(i / 28 + 2) * 32 + (i % 28) + 2] = d1[b * 784 + i];
    __syncthreads();
    for (int o = threadIdx.x; o < 16 * 196; o += 256) {
        int oc = o / 196;
        int r = o % 196;
        int i = r / 14, j = r % 14;
        float wv[25];
#pragma unroll
        for (int q = 0; q < 25; ++q) wv[q] = ws[oc * 25 + q];
        float patch[6][6];
#pragma unroll
        for (int q = 0; q < 6; ++q)
#pragma unroll
            for (int cc = 0; cc < 6; ++cc)
                patch[q][cc] = img2[(2 * i + q) * 32 + 2 * j + cc];
        float bv = bs[oc];
        float m = 0.f;
#pragma unroll
        for (int py = 0; py < 2; ++py)
#pragma unroll
            for (int px = 0; px < 2; ++px) {
                float s = bv;
#pragma unroll
                for (int dy = 0; dy < 5; ++dy)
#pragma unroll
                    for (int dx = 0; dx < 5; ++dx)
                        s += wv[dy * 5 + dx] * patch[py + dy][px + dx];
                m = fmaxf(m, s);
            }
        h1[(b * 16 + oc) * 196 + r] = m;
    }
}

__global__ __launch_bounds__(256) void k_deform2(const float* __restrict__ h1,  // (B,16,14,14)
                                                 const float* __restrict__ w2,  // (32,16,3,3)
                                                 float* __restrict__ d2) {
    __shared__ float imgp[16][16][16];  // (ic, y+1, x+1) zero-padded; 16KB
    __shared__ float ws2[32 * 145];     // [oc]: 144 weights + 1 pad
    __shared__ _Float16 offbuf[6272];   // conv output (32,14,14), fp16
    int b = blockIdx.x;
    int t = threadIdx.x;
    for (int i = t; i < 4096; i += 256) ((float*)imgp)[i] = 0.f;
    for (int i = t; i < 4608; i += 256) {
        int oc = i / 144, rem = i % 144;
        ws2[oc * 145 + rem] = w2[i];
    }
    __syncthreads();
    for (int i = t; i < 3136; i += 256) {
        int ic = i / 196, r = i % 196;
        imgp[ic][r / 14 + 1][r % 14 + 1] = h1[b * 3136 + i];
    }
    __syncthreads();

    // ---- phase A: offset conv -> offbuf ----
    if (t < 224) {
        int ocg = t & 15, row = t >> 4;
        int oc0 = ocg * 2, oc1 = oc0 + 1;
        float acc0[14], acc1[14];
#pragma unroll
        for (int c = 0; c < 14; ++c) { acc0[c] = 0.f; acc1[c] = 0.f; }
        for (int ic = 0; ic < 16; ++ic) {
            float rr_[3][16];
#pragma unroll
            for (int dy = 0; dy < 3; ++dy) {
                const float4* rp = reinterpret_cast<const float4*>(&imgp[ic][row + dy][0]);
#pragma unroll
                for (int q = 0; q < 4; ++q) {
                    float4 v = rp[q];
                    rr_[dy][q * 4 + 0] = v.x;
                    rr_[dy][q * 4 + 1] = v.y;
                    rr_[dy][q * 4 + 2] = v.z;
                    rr_[dy][q * 4 + 3] = v.w;
                }
            }
            float wa[9], wb[9];
            const float* wA = &ws2[oc0 * 145 + ic * 9];
            const float* wB = &ws2[oc1 * 145 + ic * 9];
#pragma unroll
            for (int q = 0; q < 9; ++q) { wa[q] = wA[q]; wb[q] = wB[q]; }
#pragma unroll
            for (int col = 0; col < 14; ++col) {
                float a0 = acc0[col], a1 = acc1[col];
#pragma unroll
                for (int dy = 0; dy < 3; ++dy)
#pragma unroll
                    for (int dx = 0; dx < 3; ++dx) {
                        float iv = rr_[dy][col + dx];
                        a0 += wa[dy * 3 + dx] * iv;
                        a1 += wb[dy * 3 + dx] * iv;
                    }
                acc0[col] = a0; acc1[col] = a1;
            }
        }
#pragma unroll
        for (int col = 0; col < 14; ++col) {
            offbuf[oc0 * 196 + row * 14 + col] = (_Float16)acc0[col];
            offbuf[oc1 * 196 + row * 14 + col] = (_Float16)acc1[col];
        }
    }
    __syncthreads();

    // ---- phase B: remap + bilinear ----
    for (int o = t; o < 3136; o += 256) {
        int c = o / 196, rem = o % 196;
        int h = rem / 14, w = rem % 14;
        int flat0 = c * 392 + h * 28 + w * 2;
        float offy = (float)offbuf[flat0];
        float offx = (float)offbuf[flat0 + 1];
        float cy = fminf(fmaxf((float)h + offy, 0.f), 13.f);
        float cx = fminf(fmaxf((float)w + offx, 0.f), 13.f);
        float y0f = floorf(cy), x0f = floorf(cx);
        int y0 = (int)y0f, x0 = (int)x0f;
        int y1 = (int)ceilf(cy), x1 = (int)ceilf(cx);
        float ty = cy - y0f, tx = cx - x0f;
        const float* ch = &imgp[c][0][0];
        float vlt = ch[(y0 + 1) * 16 + x0 + 1], vrt = ch[(y0 + 1) * 16 + x1 + 1];
        float vlb = ch[(y1 + 1) * 16 + x0 + 1], vrb = ch[(y1 + 1) * 16 + x1 + 1];
        float vt = vlt + (vrt - vlt) * tx;
        float vb = vlb + (vrb - vlb) * tx;
        d2[b * 3136 + o] = vt + (vb - vt) * ty;
    }
}

// conv2 weights fp32 OIHW(32,16,5,5) -> bf16 [spair=13][oc=32][k=32] (k = sl*16+ic,
// shift s = spair*2+sl, s>=25 zero-padded)
__global__ __launch_bounds__(256) void k_prep_w2(const float* __restrict__ w,
                                                 __hip_bfloat16* __restrict__ wq) {
    int e = blockIdx.x * 256 + threadIdx.x;
    if (e < 13312) {
        int spair = e >> 10, rem = e & 1023;
        int oc = rem >> 5, k = rem & 31;
        int sl = k >> 4, ic = k & 15;
        int s = spair * 2 + sl;
        float v = (s < 25) ? w[(oc * 16 + ic) * 25 + s] : 0.f;
        wq[e] = __float2bfloat16(v);
    }
}

__global__ __launch_bounds__(256) void k_conv2(const float* __restrict__ d2,          // (B,16,14,14)
                                               const __hip_bfloat16* __restrict__ wq, // [13][32][32]
                                               const float* __restrict__ bias,        // (32)
                                               float* __restrict__ h2) {              // (B,32,7,7)
    __shared__ __align__(16) __hip_bfloat16 img[18 * 20 * 24];   // [y][x][icpad24]
    __shared__ __align__(16) __hip_bfloat16 obuf[32 * 14 * 16];  // [oc][y][x], post-relu
    int b = blockIdx.x, t = threadIdx.x;
    for (int i = t; i < 4320; i += 256) ((unsigned int*)img)[i] = 0u;
    __syncthreads();
    for (int i = t; i < 3136; i += 256) {
        int ic = i / 196, r = i % 196, y = r / 14, x = r % 14;
        img[((y + 2) * 20 + (x + 2)) * 24 + ic] = __float2bfloat16(d2[b * 3136 + i]);
    }
    __syncthreads();

    int w = t >> 6, li = t & 63;
    int och = w & 1, y0c = (w >> 1) * 7;   // wave -> (oc half, 7 output rows)
    int lx = li & 15, lg = li >> 4, sl = li >> 5, ic0g = lg & 1;

    // preload A-frags (weights); same addrs for all blocks -> L2
    const bf16x8* wv = (const bf16x8*)wq;
    bf16x8 af[13];
#pragma unroll
    for (int sp = 0; sp < 13; ++sp)
        af[sp] = wv[(sp * 32 + och * 16 + lx) * 4 + lg];

    f32x4 acc[7];
#pragma unroll
    for (int y = 0; y < 7; ++y) acc[y] = (f32x4){0.f, 0.f, 0.f, 0.f};

    const bf16x8* ib = (const bf16x8*)img;
#pragma unroll
    for (int sp = 0; sp < 13; ++sp) {
        int s0 = 2 * sp + sl;
        int dy = s0 / 5, dx = s0 % 5;
        if (s0 >= 25) { dy = 0; dx = 0; }  // fake shift: weights are zero
        int base = (y0c + dy) * 60 + (lx + dx) * 3 + ic0g;  // bf16x8 units
#pragma unroll
        for (int y = 0; y < 7; ++y) {
            bf16x8 bf = ib[base + y * 60];
            acc[y] = __builtin_amdgcn_mfma_f32_16x16x32_bf16(af[sp], bf, acc[y], 0, 0, 0);
        }
    }

    // epilogue: bias + relu -> obuf (cols 14,15 are garbage, never pooled)
#pragma unroll
    for (int y = 0; y < 7; ++y) {
        int yy = y0c + y;
#pragma unroll
        for (int r = 0; r < 4; ++r) {
            int oc = och * 16 + lg * 4 + r;
            float v = fmaxf(acc[y][r] + bias[oc], 0.f);
            obuf[(oc * 14 + yy) * 16 + lx] = __float2bfloat16(v);
        }
    }
    __syncthreads();

    for (int o = t; o < 1568; o += 256) {
        int oc = o / 49, p = o % 49, i = p / 7, j = p % 7;
        const __hip_bfloat16* q = &obuf[(oc * 14 + 2 * i) * 16 + 2 * j];
        float m = fmaxf(fmaxf(__bfloat162float(q[0]), __bfloat162float(q[1])),
                        fmaxf(__bfloat162float(q[16]), __bfloat162float(q[17])));
        h2[b * 1568 + o] = m;
    }
}

__global__ __launch_bounds__(64) void k_fc(const float* __restrict__ h2,  // (B,1568)
                                           const float* __restrict__ fw,  // (10,1568)
                                           const float* __restrict__ fb,  // (10)
                                           float* __restrict__ out) {     // (B,10)
    int b = blockIdx.x;
    int lane = threadIdx.x;
    float acc[10];
#pragma unroll
    for (int o = 0; o < 10; ++o) acc[o] = 0.f;
    const float* row = h2 + b * 1568;
    for (int k = lane; k < 1568; k += 64) {
        float v = row[k];
#pragma unroll
        for (int o = 0; o < 10; ++o) acc[o] += v * fw[o * 1568 + k];
    }
#pragma unroll
    for (int o = 0; o < 10; ++o) {
        float s = acc[o];
#pragma unroll
        for (int m = 32; m > 0; m >>= 1) s += __shfl_xor(s, m);
        if (lane == 0) out[b * 10 + o] = s + fb[o];
    }
}

extern "C" void kernel_launch(void* const* d_in, const int* in_sizes, int n_in,
                              void* d_out, int out_size, void* d_ws, size_t ws_size,
                              hipStream_t stream) {
    const float* x       = (const float*)d_in[0];
    const float* off1_w  = (const float*)d_in[1];
    const float* conv1_w = (const float*)d_in[2];
    const float* conv1_b = (const float*)d_in[3];
    const float* off2_w  = (const float*)d_in[4];
    const float* conv2_w = (const float*)d_in[5];
    const float* conv2_b = (const float*)d_in[6];
    const float* fc_w    = (const float*)d_in[7];
    const float* fc_b    = (const float*)d_in[8];
    float* out = (float*)d_out;

    char* ws = (char*)d_ws;
    size_t R1 = 0;
    size_t R2 = R1 + (size_t)B_IMG * 3136 * 4;
    size_t R3 = R2 + (size_t)B_IMG * 3136 * 4;
    size_t R4 = R3 + (size_t)B_IMG * 1568 * 4;
    float* d1 = (float*)(ws + R1);
    float* h1 = (float*)(ws + R2);
    float* d2 = (float*)(ws + R1);  // reuse R1 (d1 dead after k_conv1)
    float* h2 = (float*)(ws + R3);
    __hip_bfloat16* wq = (__hip_bfloat16*)(ws + R4);  // 13312 bf16 = 26.6 KB

    k_prep_w2<<<52, 256, 0, stream>>>(conv2_w, wq);
    k_deform1<<<B_IMG, 256, 0, stream>>>(x, off1_w, d1);
    k_conv1<<<B_IMG, 256, 0, stream>>>(d1, conv1_w, conv1_b, h1);
    k_deform2<<<B_IMG, 256, 0, stream>>>(h1, off2_w, d2);
    k_conv2<<<B_IMG, 256, 0, stream>>>(d2, wq, conv2_b, h2);
    k_fc<<<B_IMG, 64, 0, stream>>>(h2, fc_w, fc_b, out);
}

// Round 6
// 97.470 us; speedup vs baseline: 7.3160x; 1.7371x over previous
//
#include <hip/hip_runtime.h>
#include <hip/hip_bf16.h>

// Fully-fused deform-conv MNIST net. B=2048, one block per image.
// k_prep: pack offset-conv2 + conv2 weights as bf16 MFMA A-operands in ws.
// k_net : deform1 -> conv1(+relu+pool) -> offset-conv(MFMA) -> remap+bilinear
//         -> conv2(MFMA shift-GEMM)+relu+pool -> FC, all in LDS.

#define B_IMG 2048

typedef short bf16x8 __attribute__((ext_vector_type(8)));
typedef float f32x4 __attribute__((ext_vector_type(4)));

// wqo [5][32][32]  : off2_w (32,16,3,3) -> k=sl*16+ic, s=2*sp+sl, s>=9 zero
// wq2 [13][32][32] : conv2_w (32,16,5,5) -> s>=25 zero
__global__ __launch_bounds__(256) void k_prep(const float* __restrict__ w_off2,
                                              const float* __restrict__ w_c2,
                                              __hip_bfloat16* __restrict__ wqo,
                                              __hip_bfloat16* __restrict__ wq2) {
    int e = blockIdx.x * 256 + threadIdx.x;
    if (e < 5120) {
        int sp = e >> 10, rem = e & 1023, oc = rem >> 5, k = rem & 31;
        int sl = k >> 4, ic = k & 15, s = 2 * sp + sl;
        wqo[e] = __float2bfloat16(s < 9 ? w_off2[(oc * 16 + ic) * 9 + s] : 0.f);
    } else if (e < 18432) {
        int e2 = e - 5120;
        int sp = e2 >> 10, rem = e2 & 1023, oc = rem >> 5, k = rem & 31;
        int sl = k >> 4, ic = k & 15, s = 2 * sp + sl;
        wq2[e2] = __float2bfloat16(s < 25 ? w_c2[(oc * 16 + ic) * 25 + s] : 0.f);
    }
}

__global__ __launch_bounds__(256) void k_net(const float* __restrict__ x,        // (B,1,28,28)
                                             const float* __restrict__ off1_w,   // (2,1,3,3)
                                             const float* __restrict__ conv1_w,  // (16,1,5,5)
                                             const float* __restrict__ conv1_b,  // (16)
                                             const __hip_bfloat16* __restrict__ wqo,
                                             const __hip_bfloat16* __restrict__ wq2,
                                             const float* __restrict__ conv2_b,  // (32)
                                             const float* __restrict__ fc_w,     // (10,1568)
                                             const float* __restrict__ fc_b,     // (10)
                                             float* __restrict__ out) {          // (B,10)
    __shared__ float h1f[16 * 196];                          // 12544 B, fp32 h1 (bilinear corners)
    __shared__ __align__(16) __hip_bfloat16 imgb[17 * 16 * 16];   // 8704 B, h1 ch-last pad1
    __shared__ __align__(16) _Float16 offbuf[6272];          // 12544 B; later: pl (f32 x 1568)
    __shared__ __align__(16) __hip_bfloat16 img2b[18 * 20 * 16];  // 11520 B, d2 ch-last pad2
    __shared__ __align__(16) char s5[14336];                 // phase0 scratch; later obuf
    __shared__ float wred[40];

    float* xs   = (float*)s5;           // [30][30] pad1, 3600 B
    float* img2 = (float*)(s5 + 3600);  // [32][32] pad2, 4096 B
    float* wsc  = (float*)(s5 + 7696);  // conv1 w, 1600 B
    float* bsc  = (float*)(s5 + 9296);  // conv1 b, 64 B
    __hip_bfloat16* obuf = (__hip_bfloat16*)s5;  // [32][14][16] post-relu conv2
    float* pl = (float*)offbuf;                  // pooled (32,7,7) flat

    int b = blockIdx.x, t = threadIdx.x;

    // ---- phase 0: zero pads, stage weights + input ----
    for (int i = t; i < 900; i += 256) xs[i] = 0.f;
    for (int i = t; i < 1024; i += 256) img2[i] = 0.f;
    for (int i = t; i < 2176; i += 256) ((unsigned int*)imgb)[i] = 0u;
    for (int i = t; i < 2880; i += 256) ((unsigned int*)img2b)[i] = 0u;
    for (int i = t; i < 400; i += 256) wsc[i] = conv1_w[i];
    if (t < 16) bsc[t] = conv1_b[t];
    __syncthreads();
    for (int i = t; i < 784; i += 256)
        xs[(i / 28 + 1) * 30 + (i % 28) + 1] = x[b * 784 + i];
    __syncthreads();

    // ---- phase 1: deform1 -> img2 (padded by 2) ----
    for (int p = t; p < 784; p += 256) {
        int h = p / 28, w = p % 28;
        float off[2];
        int flat0 = h * 56 + w * 2;
#pragma unroll
        for (int k = 0; k < 2; ++k) {
            int flat = flat0 + k;
            int c = flat / 784;
            int r = flat % 784;
            int hh = r / 28, ww = r % 28;
            float s = 0.f;
#pragma unroll
            for (int dy = 0; dy < 3; ++dy)
#pragma unroll
                for (int dx = 0; dx < 3; ++dx)
                    s += off1_w[c * 9 + dy * 3 + dx] * xs[(hh + dy) * 30 + ww + dx];
            off[k] = s;
        }
        float cy = fminf(fmaxf((float)h + off[0], 0.f), 27.f);
        float cx = fminf(fmaxf((float)w + off[1], 0.f), 27.f);
        float y0f = floorf(cy), x0f = floorf(cx);
        int y0 = (int)y0f, x0 = (int)x0f;
        int y1 = (int)ceilf(cy), x1 = (int)ceilf(cx);
        float ty = cy - y0f, tx = cx - x0f;
        float vlt = xs[(y0 + 1) * 30 + x0 + 1], vrt = xs[(y0 + 1) * 30 + x1 + 1];
        float vlb = xs[(y1 + 1) * 30 + x0 + 1], vrb = xs[(y1 + 1) * 30 + x1 + 1];
        float vt = vlt + (vrt - vlt) * tx;
        float vb = vlb + (vrb - vlb) * tx;
        img2[(h + 2) * 32 + (w + 2)] = vt + (vb - vt) * ty;
    }
    __syncthreads();

    // ---- phase 2: conv1 5x5 p2 + relu + pool -> h1f (fp32) + imgb (bf16 ch-last) ----
    for (int o = t; o < 3136; o += 256) {
        int oc = o & 15, r = o >> 4;  // oc-inner: 16-lane groups share patch addrs
        int i = r / 14, j = r % 14;
        float wv[25];
#pragma unroll
        for (int q = 0; q < 25; ++q) wv[q] = wsc[oc * 25 + q];
        float patch[6][6];
#pragma unroll
        for (int q = 0; q < 6; ++q)
#pragma unroll
            for (int cc = 0; cc < 6; ++cc)
                patch[q][cc] = img2[(2 * i + q) * 32 + 2 * j + cc];
        float bv = bsc[oc];
        float m = 0.f;
#pragma unroll
        for (int py = 0; py < 2; ++py)
#pragma unroll
            for (int px = 0; px < 2; ++px) {
                float s = bv;
#pragma unroll
                for (int dy = 0; dy < 5; ++dy)
#pragma unroll
                    for (int dx = 0; dx < 5; ++dx)
                        s += wv[dy * 5 + dx] * patch[py + dy][px + dx];
                m = fmaxf(m, s);
            }
        h1f[oc * 196 + r] = m;
        imgb[(i + 1) * 256 + (j + 1) * 16 + oc] = __float2bfloat16(m);
    }
    __syncthreads();

    int wv_ = t >> 6, li = t & 63;
    int och = wv_ & 1, y0c = (wv_ >> 1) * 7;  // wave -> (oc half, 7 rows)
    int lx = li & 15, lg = li >> 4;

    // ---- phase A: offset conv (32,14,14) via MFMA shift-GEMM -> offbuf ----
    {
        const bf16x8* wA = (const bf16x8*)wqo;
        bf16x8 afA[5];
#pragma unroll
        for (int sp = 0; sp < 5; ++sp)
            afA[sp] = wA[(sp * 32 + och * 16 + lx) * 4 + lg];
        int slA = lg >> 1, icsel = lg & 1;
        f32x4 acc[7];
#pragma unroll
        for (int y = 0; y < 7; ++y) acc[y] = (f32x4){0.f, 0.f, 0.f, 0.f};
        const bf16x8* ib = (const bf16x8*)imgb;
#pragma unroll
        for (int sp = 0; sp < 5; ++sp) {
            int s0 = 2 * sp + slA;
            int dy = s0 / 3, dx = s0 % 3;
            if (s0 >= 9) { dy = 0; dx = 0; }  // zero-weight pad step
            int base = dy * 32 + (lx + dx) * 2 + icsel;
#pragma unroll
            for (int y = 0; y < 7; ++y) {
                bf16x8 bfr = ib[base + (y0c + y) * 32];
                acc[y] = __builtin_amdgcn_mfma_f32_16x16x32_bf16(afA[sp], bfr, acc[y], 0, 0, 0);
            }
        }
        if (lx < 14) {
#pragma unroll
            for (int y = 0; y < 7; ++y) {
                int yy = y0c + y;
#pragma unroll
                for (int r = 0; r < 4; ++r) {
                    int oc = och * 16 + lg * 4 + r;
                    offbuf[oc * 196 + yy * 14 + lx] = (_Float16)acc[y][r];
                }
            }
        }
    }
    __syncthreads();

    // ---- phase B: raw-reshape remap + bilinear (fp32 corners) -> img2b ----
    for (int o = t; o < 3136; o += 256) {
        int c = o / 196, rem = o % 196;
        int h = rem / 14, w = rem % 14;
        int flat0 = c * 392 + h * 28 + w * 2;
        float offy = (float)offbuf[flat0];
        float offx = (float)offbuf[flat0 + 1];
        float cy = fminf(fmaxf((float)h + offy, 0.f), 13.f);
        float cx = fminf(fmaxf((float)w + offx, 0.f), 13.f);
        float y0f = floorf(cy), x0f = floorf(cx);
        int y0 = (int)y0f, x0 = (int)x0f;
        int y1 = (int)ceilf(cy), x1 = (int)ceilf(cx);
        float ty = cy - y0f, tx = cx - x0f;
        const float* ch = h1f + c * 196;
        float vlt = ch[y0 * 14 + x0], vrt = ch[y0 * 14 + x1];
        float vlb = ch[y1 * 14 + x0], vrb = ch[y1 * 14 + x1];
        float vt = vlt + (vrt - vlt) * tx;
        float vb = vlb + (vrb - vlb) * tx;
        img2b[((h + 2) * 20 + (w + 2)) * 16 + c] = __float2bfloat16(vt + (vb - vt) * ty);
    }
    __syncthreads();

    // ---- phase C: conv2 via MFMA shift-GEMM + bias + relu -> obuf ----
    {
        const bf16x8* wB = (const bf16x8*)wq2;
        bf16x8 af[13];
#pragma unroll
        for (int sp = 0; sp < 13; ++sp)
            af[sp] = wB[(sp * 32 + och * 16 + lx) * 4 + lg];
        int sl = lg >> 1, icg = lg & 1;
        f32x4 acc[7];
#pragma unroll
        for (int y = 0; y < 7; ++y) acc[y] = (f32x4){0.f, 0.f, 0.f, 0.f};
        const bf16x8* ib2 = (const bf16x8*)img2b;
#pragma unroll
        for (int sp = 0; sp < 13; ++sp) {
            int s0 = 2 * sp + sl;
            int dy = s0 / 5, dx = s0 % 5;
            if (s0 >= 25) { dy = 0; dx = 0; }
            int base = (y0c + dy) * 40 + (lx + dx) * 2 + icg;
#pragma unroll
            for (int y = 0; y < 7; ++y) {
                bf16x8 bfr = ib2[base + y * 40];
                acc[y] = __builtin_amdgcn_mfma_f32_16x16x32_bf16(af[sp], bfr, acc[y], 0, 0, 0);
            }
        }
#pragma unroll
        for (int y = 0; y < 7; ++y) {
            int yy = y0c + y;
#pragma unroll
            for (int r = 0; r < 4; ++r) {
                int oc = och * 16 + lg * 4 + r;
                float v = fmaxf(acc[y][r] + conv2_b[oc], 0.f);
                obuf[(oc * 14 + yy) * 16 + lx] = __float2bfloat16(v);
            }
        }
    }
    __syncthreads();

    // ---- phase D: maxpool -> pl (fp32, overlays offbuf) ----
    for (int o = t; o < 1568; o += 256) {
        int oc = o / 49, p = o % 49, i = p / 7, j = p % 7;
        const __hip_bfloat16* q = &obuf[(oc * 14 + 2 * i) * 16 + 2 * j];
        float m = fmaxf(fmaxf(__bfloat162float(q[0]), __bfloat162float(q[1])),
                        fmaxf(__bfloat162float(q[16]), __bfloat162float(q[17])));
        pl[o] = m;
    }
    __syncthreads();

    // ---- phase E: FC 1568->10 ----
    float facc[10];
#pragma unroll
    for (int o = 0; o < 10; ++o) facc[o] = 0.f;
    for (int k = t; k < 1568; k += 256) {
        float v = pl[k];
#pragma unroll
        for (int o = 0; o < 10; ++o) facc[o] += v * fc_w[o * 1568 + k];
    }
#pragma unroll
    for (int o = 0; o < 10; ++o) {
        float s = facc[o];
#pragma unroll
        for (int m = 32; m > 0; m >>= 1) s += __shfl_xor(s, m);
        if (li == 0) wred[o * 4 + wv_] = s;
    }
    __syncthreads();
    if (t < 10)
        out[b * 10 + t] = fc_b[t] + wred[t * 4] + wred[t * 4 + 1] + wred[t * 4 + 2] + wred[t * 4 + 3];
}

extern "C" void kernel_launch(void* const* d_in, const int* in_sizes, int n_in,
                              void* d_out, int out_size, void* d_ws, size_t ws_size,
                              hipStream_t stream) {
    const float* x       = (const float*)d_in[0];
    const float* off1_w  = (const float*)d_in[1];
    const float* conv1_w = (const float*)d_in[2];
    const float* conv1_b = (const float*)d_in[3];
    const float* off2_w  = (const float*)d_in[4];
    const float* conv2_w = (const float*)d_in[5];
    const float* conv2_b = (const float*)d_in[6];
    const float* fc_w    = (const float*)d_in[7];
    const float* fc_b    = (const float*)d_in[8];
    float* out = (float*)d_out;

    char* ws = (char*)d_ws;
    __hip_bfloat16* wqo = (__hip_bfloat16*)ws;             // 5120 bf16  = 10240 B
    __hip_bfloat16* wq2 = (__hip_bfloat16*)(ws + 10240);   // 13312 bf16 = 26624 B

    k_prep<<<72, 256, 0, stream>>>(off2_w, conv2_w, wqo, wq2);
    k_net<<<B_IMG, 256, 0, stream>>>(x, off1_w, conv1_w, conv1_b, wqo, wq2,
                                     conv2_b, fc_w, fc_b, out);
}

// Round 7
// 72.883 us; speedup vs baseline: 9.7840x; 1.3373x over previous
//
#include <hip/hip_runtime.h>
#include <hip/hip_bf16.h>

// Fully-fused deform-conv MNIST net. B=2048, one block per image.
// LDS overlaid by phase lifetime: 34,720 B -> 4 blocks/CU (16 waves/CU).
//   s5    : xs|img2|wsc|bsc (ph0-2) -> offbuf (phA-B) -> obuf (phC-D)
//   imgb  : bf16 ch-last h1 (ph2-B; also bilinear corner source in phB)
//   img2b : bf16 ch-last d2 (phB-C) -> pl fp32 pooled (phD-E)

#define B_IMG 2048

typedef short bf16x8 __attribute__((ext_vector_type(8)));
typedef float f32x4 __attribute__((ext_vector_type(4)));

// wqo [5][32][32]  : off2_w (32,16,3,3) -> k=sl*16+ic, s=2*sp+sl, s>=9 zero
// wq2 [13][32][32] : conv2_w (32,16,5,5) -> s>=25 zero
__global__ __launch_bounds__(256) void k_prep(const float* __restrict__ w_off2,
                                              const float* __restrict__ w_c2,
                                              __hip_bfloat16* __restrict__ wqo,
                                              __hip_bfloat16* __restrict__ wq2) {
    int e = blockIdx.x * 256 + threadIdx.x;
    if (e < 5120) {
        int sp = e >> 10, rem = e & 1023, oc = rem >> 5, k = rem & 31;
        int sl = k >> 4, ic = k & 15, s = 2 * sp + sl;
        wqo[e] = __float2bfloat16(s < 9 ? w_off2[(oc * 16 + ic) * 9 + s] : 0.f);
    } else if (e < 18432) {
        int e2 = e - 5120;
        int sp = e2 >> 10, rem = e2 & 1023, oc = rem >> 5, k = rem & 31;
        int sl = k >> 4, ic = k & 15, s = 2 * sp + sl;
        wq2[e2] = __float2bfloat16(s < 25 ? w_c2[(oc * 16 + ic) * 25 + s] : 0.f);
    }
}

__global__ __launch_bounds__(256, 4) void k_net(const float* __restrict__ x,        // (B,1,28,28)
                                                const float* __restrict__ off1_w,   // (2,1,3,3)
                                                const float* __restrict__ conv1_w,  // (16,1,5,5)
                                                const float* __restrict__ conv1_b,  // (16)
                                                const __hip_bfloat16* __restrict__ wqo,
                                                const __hip_bfloat16* __restrict__ wq2,
                                                const float* __restrict__ conv2_b,  // (32)
                                                const float* __restrict__ fc_w,     // (10,1568)
                                                const float* __restrict__ fc_b,     // (10)
                                                float* __restrict__ out) {          // (B,10)
    __shared__ __align__(16) char s5[14336];                      // multi-use scratch
    __shared__ __align__(16) __hip_bfloat16 imgb[17 * 16 * 16];   // 8704 B
    __shared__ __align__(16) __hip_bfloat16 img2b[18 * 20 * 16];  // 11520 B
    __shared__ float wred[40];

    float* xs   = (float*)s5;            // [30][30] pad1, 3600 B
    float* img2 = (float*)(s5 + 3600);   // [32][32] pad2, 4096 B
    float* wsc  = (float*)(s5 + 7696);   // conv1 w, 1600 B
    float* bsc  = (float*)(s5 + 9296);   // conv1 b, 64 B
    _Float16* offbuf = (_Float16*)s5;            // phase A-B, 12544 B
    __hip_bfloat16* obuf = (__hip_bfloat16*)s5;  // phase C-D, 14336 B
    float* pl = (float*)img2b;                   // phase D-E, 6272 B

    int b = blockIdx.x, t = threadIdx.x;

    // ---- phase 0: zero pads, stage weights + input ----
    for (int i = t; i < 900; i += 256) xs[i] = 0.f;
    for (int i = t; i < 1024; i += 256) img2[i] = 0.f;
    for (int i = t; i < 2176; i += 256) ((unsigned int*)imgb)[i] = 0u;
    for (int i = t; i < 2880; i += 256) ((unsigned int*)img2b)[i] = 0u;
    for (int i = t; i < 400; i += 256) wsc[i] = conv1_w[i];
    if (t < 16) bsc[t] = conv1_b[t];
    __syncthreads();
    for (int i = t; i < 784; i += 256)
        xs[(i / 28 + 1) * 30 + (i % 28) + 1] = x[b * 784 + i];
    __syncthreads();

    // ---- phase 1: deform1 -> img2 (padded by 2) ----
    for (int p = t; p < 784; p += 256) {
        int h = p / 28, w = p % 28;
        float off[2];
        int flat0 = h * 56 + w * 2;
#pragma unroll
        for (int k = 0; k < 2; ++k) {
            int flat = flat0 + k;
            int c = flat / 784;
            int r = flat % 784;
            int hh = r / 28, ww = r % 28;
            float s = 0.f;
#pragma unroll
            for (int dy = 0; dy < 3; ++dy)
#pragma unroll
                for (int dx = 0; dx < 3; ++dx)
                    s += off1_w[c * 9 + dy * 3 + dx] * xs[(hh + dy) * 30 + ww + dx];
            off[k] = s;
        }
        float cy = fminf(fmaxf((float)h + off[0], 0.f), 27.f);
        float cx = fminf(fmaxf((float)w + off[1], 0.f), 27.f);
        float y0f = floorf(cy), x0f = floorf(cx);
        int y0 = (int)y0f, x0 = (int)x0f;
        int y1 = (int)ceilf(cy), x1 = (int)ceilf(cx);
        float ty = cy - y0f, tx = cx - x0f;
        float vlt = xs[(y0 + 1) * 30 + x0 + 1], vrt = xs[(y0 + 1) * 30 + x1 + 1];
        float vlb = xs[(y1 + 1) * 30 + x0 + 1], vrb = xs[(y1 + 1) * 30 + x1 + 1];
        float vt = vlt + (vrt - vlt) * tx;
        float vb = vlb + (vrb - vlb) * tx;
        img2[(h + 2) * 32 + (w + 2)] = vt + (vb - vt) * ty;
    }
    __syncthreads();

    // ---- phase 2: conv1 5x5 p2 + relu + pool -> imgb (bf16 ch-last) ----
    // item = (oc fixed per thread, row i, jp) -> 2 adjacent pooled outputs
    {
        int oc = t & 15;
        float wv[25];
#pragma unroll
        for (int q = 0; q < 25; ++q) wv[q] = wsc[oc * 25 + q];
        float bv = bsc[oc];
        for (int o = t; o < 1568; o += 256) {
            int r = o >> 4;  // 0..97
            int i = r / 7, jp = r % 7;
            float s_[2][4];
#pragma unroll
            for (int py = 0; py < 2; ++py)
#pragma unroll
                for (int cx = 0; cx < 4; ++cx) s_[py][cx] = bv;
#pragma unroll
            for (int q = 0; q < 6; ++q) {  // stream patch rows
                const float4* rp = (const float4*)&img2[(2 * i + q) * 32 + 4 * jp];
                float4 ra = rp[0], rb = rp[1];
                float row[8] = {ra.x, ra.y, ra.z, ra.w, rb.x, rb.y, rb.z, rb.w};
#pragma unroll
                for (int py = 0; py < 2; ++py) {
                    int dy = q - py;
                    if (dy >= 0 && dy < 5) {
#pragma unroll
                        for (int cx = 0; cx < 4; ++cx)
#pragma unroll
                            for (int dx = 0; dx < 5; ++dx)
                                s_[py][cx] += wv[dy * 5 + dx] * row[cx + dx];
                    }
                }
            }
            float m0 = fmaxf(fmaxf(s_[0][0], s_[0][1]), fmaxf(s_[1][0], s_[1][1]));
            float m1 = fmaxf(fmaxf(s_[0][2], s_[0][3]), fmaxf(s_[1][2], s_[1][3]));
            m0 = fmaxf(m0, 0.f);
            m1 = fmaxf(m1, 0.f);
            imgb[(i + 1) * 256 + (2 * jp + 1) * 16 + oc] = __float2bfloat16(m0);
            imgb[(i + 1) * 256 + (2 * jp + 2) * 16 + oc] = __float2bfloat16(m1);
        }
    }
    __syncthreads();

    int wv_ = t >> 6, li = t & 63;
    int och = wv_ & 1, y0c = (wv_ >> 1) * 7;  // wave -> (oc half, 7 rows)
    int lx = li & 15, lg = li >> 4;

    // ---- phase A: offset conv (32,14,14) via MFMA shift-GEMM -> offbuf ----
    {
        const bf16x8* wA = (const bf16x8*)wqo;
        bf16x8 afA[5];
#pragma unroll
        for (int sp = 0; sp < 5; ++sp)
            afA[sp] = wA[(sp * 32 + och * 16 + lx) * 4 + lg];
        int slA = lg >> 1, icsel = lg & 1;
        f32x4 acc[7];
#pragma unroll
        for (int y = 0; y < 7; ++y) acc[y] = (f32x4){0.f, 0.f, 0.f, 0.f};
        const bf16x8* ib = (const bf16x8*)imgb;
#pragma unroll
        for (int sp = 0; sp < 5; ++sp) {
            int s0 = 2 * sp + slA;
            int dy = s0 / 3, dx = s0 % 3;
            if (s0 >= 9) { dy = 0; dx = 0; }  // zero-weight pad step
            int base = dy * 32 + (lx + dx) * 2 + icsel;
#pragma unroll
            for (int y = 0; y < 7; ++y) {
                bf16x8 bfr = ib[base + (y0c + y) * 32];
                acc[y] = __builtin_amdgcn_mfma_f32_16x16x32_bf16(afA[sp], bfr, acc[y], 0, 0, 0);
            }
        }
        if (lx < 14) {
#pragma unroll
            for (int y = 0; y < 7; ++y) {
                int yy = y0c + y;
#pragma unroll
                for (int r = 0; r < 4; ++r) {
                    int oc = och * 16 + lg * 4 + r;
                    offbuf[oc * 196 + yy * 14 + lx] = (_Float16)acc[y][r];
                }
            }
        }
    }
    __syncthreads();

    // ---- phase B: raw-reshape remap + bilinear (bf16 corners from imgb) -> img2b ----
    for (int o = t; o < 3136; o += 256) {
        int c = o / 196, rem = o % 196;
        int h = rem / 14, w = rem % 14;
        int flat0 = c * 392 + h * 28 + w * 2;
        float offy = (float)offbuf[flat0];
        float offx = (float)offbuf[flat0 + 1];
        float cy = fminf(fmaxf((float)h + offy, 0.f), 13.f);
        float cx = fminf(fmaxf((float)w + offx, 0.f), 13.f);
        float y0f = floorf(cy), x0f = floorf(cx);
        int y0 = (int)y0f, x0 = (int)x0f;
        int y1 = (int)ceilf(cy), x1 = (int)ceilf(cx);
        float ty = cy - y0f, tx = cx - x0f;
        float vlt = __bfloat162float(imgb[(y0 + 1) * 256 + (x0 + 1) * 16 + c]);
        float vrt = __bfloat162float(imgb[(y0 + 1) * 256 + (x1 + 1) * 16 + c]);
        float vlb = __bfloat162float(imgb[(y1 + 1) * 256 + (x0 + 1) * 16 + c]);
        float vrb = __bfloat162float(imgb[(y1 + 1) * 256 + (x1 + 1) * 16 + c]);
        float vt = vlt + (vrt - vlt) * tx;
        float vb = vlb + (vrb - vlb) * tx;
        img2b[((h + 2) * 20 + (w + 2)) * 16 + c] = __float2bfloat16(vt + (vb - vt) * ty);
    }
    __syncthreads();

    // ---- phase C: conv2 via MFMA shift-GEMM + bias + relu -> obuf ----
    {
        const bf16x8* wB = (const bf16x8*)wq2;
        bf16x8 af[13];
#pragma unroll
        for (int sp = 0; sp < 13; ++sp)
            af[sp] = wB[(sp * 32 + och * 16 + lx) * 4 + lg];
        int sl = lg >> 1, icg = lg & 1;
        f32x4 acc[7];
#pragma unroll
        for (int y = 0; y < 7; ++y) acc[y] = (f32x4){0.f, 0.f, 0.f, 0.f};
        const bf16x8* ib2 = (const bf16x8*)img2b;
#pragma unroll
        for (int sp = 0; sp < 13; ++sp) {
            int s0 = 2 * sp + sl;
            int dy = s0 / 5, dx = s0 % 5;
            if (s0 >= 25) { dy = 0; dx = 0; }
            int base = (y0c + dy) * 40 + (lx + dx) * 2 + icg;
#pragma unroll
            for (int y = 0; y < 7; ++y) {
                bf16x8 bfr = ib2[base + y * 40];
                acc[y] = __builtin_amdgcn_mfma_f32_16x16x32_bf16(af[sp], bfr, acc[y], 0, 0, 0);
            }
        }
#pragma unroll
        for (int y = 0; y < 7; ++y) {
            int yy = y0c + y;
#pragma unroll
            for (int r = 0; r < 4; ++r) {
                int oc = och * 16 + lg * 4 + r;
                float v = fmaxf(acc[y][r] + conv2_b[oc], 0.f);
                obuf[(oc * 14 + yy) * 16 + lx] = __float2bfloat16(v);
            }
        }
    }
    __syncthreads();

    // ---- phase D: maxpool -> pl (fp32, overlays img2b) ----
    for (int o = t; o < 1568; o += 256) {
        int oc = o / 49, p = o % 49, i = p / 7, j = p % 7;
        const __hip_bfloat16* q = &obuf[(oc * 14 + 2 * i) * 16 + 2 * j];
        float m = fmaxf(fmaxf(__bfloat162float(q[0]), __bfloat162float(q[1])),
                        fmaxf(__bfloat162float(q[16]), __bfloat162float(q[17])));
        pl[o] = m;
    }
    __syncthreads();

    // ---- phase E: FC 1568->10 ----
    float facc[10];
#pragma unroll
    for (int o = 0; o < 10; ++o) facc[o] = 0.f;
    for (int k = t; k < 1568; k += 256) {
        float v = pl[k];
#pragma unroll
        for (int o = 0; o < 10; ++o) facc[o] += v * fc_w[o * 1568 + k];
    }
#pragma unroll
    for (int o = 0; o < 10; ++o) {
        float s = facc[o];
#pragma unroll
        for (int m = 32; m > 0; m >>= 1) s += __shfl_xor(s, m);
        if (li == 0) wred[o * 4 + wv_] = s;
    }
    __syncthreads();
    if (t < 10)
        out[b * 10 + t] = fc_b[t] + wred[t * 4] + wred[t * 4 + 1] + wred[t * 4 + 2] + wred[t * 4 + 3];
}

extern "C" void kernel_launch(void* const* d_in, const int* in_sizes, int n_in,
                              void* d_out, int out_size, void* d_ws, size_t ws_size,
                              hipStream_t stream) {
    const float* x       = (const float*)d_in[0];
    const float* off1_w  = (const float*)d_in[1];
    const float* conv1_w = (const float*)d_in[2];
    const float* conv1_b = (const float*)d_in[3];
    const float* off2_w  = (const float*)d_in[4];
    const float* conv2_w = (const float*)d_in[5];
    const float* conv2_b = (const float*)d_in[6];
    const float* fc_w    = (const float*)d_in[7];
    const float* fc_b    = (const float*)d_in[8];
    float* out = (float*)d_out;

    char* ws = (char*)d_ws;
    __hip_bfloat16* wqo = (__hip_bfloat16*)ws;             // 5120 bf16  = 10240 B
    __hip_bfloat16* wq2 = (__hip_bfloat16*)(ws + 10240);   // 13312 bf16 = 26624 B

    k_prep<<<72, 256, 0, stream>>>(off2_w, conv2_w, wqo, wq2);
    k_net<<<B_IMG, 256, 0, stream>>>(x, off1_w, conv1_w, conv1_b, wqo, wq2,
                                     conv2_b, fc_w, fc_b, out);
}

// Round 8
// 70.079 us; speedup vs baseline: 10.1755x; 1.0400x over previous
//
#include <hip/hip_runtime.h>
#include <hip/hip_bf16.h>

// Fully-fused deform-conv MNIST net. B=2048, one block per image.
// LDS = exactly 32768 B -> 5 blocks/CU. Pool fused into conv2 epilogue.
//   s5    : xs|img2|wsc|bsc (ph0-2) -> offbuf (phA-B) -> pl+wred (phC-E)
//   imgb  : bf16 ch-last h1 (ph2-B)
//   img2b : bf16 ch-last d2 (phB-C)

#define B_IMG 2048

typedef short bf16x8 __attribute__((ext_vector_type(8)));
typedef float f32x4 __attribute__((ext_vector_type(4)));

// wqo [5][32][32]  : off2_w (32,16,3,3) -> k=sl*16+ic, s=2*sp+sl, s>=9 zero
// wq2 [13][32][32] : conv2_w (32,16,5,5) -> s>=25 zero
__global__ __launch_bounds__(256) void k_prep(const float* __restrict__ w_off2,
                                              const float* __restrict__ w_c2,
                                              __hip_bfloat16* __restrict__ wqo,
                                              __hip_bfloat16* __restrict__ wq2) {
    int e = blockIdx.x * 256 + threadIdx.x;
    if (e < 5120) {
        int sp = e >> 10, rem = e & 1023, oc = rem >> 5, k = rem & 31;
        int sl = k >> 4, ic = k & 15, s = 2 * sp + sl;
        wqo[e] = __float2bfloat16(s < 9 ? w_off2[(oc * 16 + ic) * 9 + s] : 0.f);
    } else if (e < 18432) {
        int e2 = e - 5120;
        int sp = e2 >> 10, rem = e2 & 1023, oc = rem >> 5, k = rem & 31;
        int sl = k >> 4, ic = k & 15, s = 2 * sp + sl;
        wq2[e2] = __float2bfloat16(s < 25 ? w_c2[(oc * 16 + ic) * 25 + s] : 0.f);
    }
}

__global__ __launch_bounds__(256, 5) void k_net(const float* __restrict__ x,        // (B,1,28,28)
                                                const float* __restrict__ off1_w,   // (2,1,3,3)
                                                const float* __restrict__ conv1_w,  // (16,1,5,5)
                                                const float* __restrict__ conv1_b,  // (16)
                                                const __hip_bfloat16* __restrict__ wqo,
                                                const __hip_bfloat16* __restrict__ wq2,
                                                const float* __restrict__ conv2_b,  // (32)
                                                const float* __restrict__ fc_w,     // (10,1568)
                                                const float* __restrict__ fc_b,     // (10)
                                                float* __restrict__ out) {          // (B,10)
    __shared__ __align__(16) char s5[12544];                      // multi-use scratch
    __shared__ __align__(16) __hip_bfloat16 imgb[17 * 16 * 16];   // 8704 B
    __shared__ __align__(16) __hip_bfloat16 img2b[18 * 20 * 16];  // 11520 B

    float* xs    = (float*)s5;            // [30][30] pad1, 3600 B
    float* img2  = (float*)(s5 + 3600);   // [32][32] pad2, 4096 B
    float* wsc   = (float*)(s5 + 7696);   // conv1 w, 1600 B
    float* bsc   = (float*)(s5 + 9296);   // conv1 b, 64 B
    _Float16* offbuf = (_Float16*)s5;     // phase A-B, 12544 B
    float* pl    = (float*)s5;            // phase C-E, 6272 B (pooled 32x7x7)
    float* wredp = (float*)(s5 + 6272);   // phase E, 160 B

    int b = blockIdx.x, t = threadIdx.x;

    // ---- phase 0: zero pads, stage weights + input ----
    for (int i = t; i < 900; i += 256) xs[i] = 0.f;
    for (int i = t; i < 1024; i += 256) img2[i] = 0.f;
    for (int i = t; i < 2176; i += 256) ((unsigned int*)imgb)[i] = 0u;
    for (int i = t; i < 2880; i += 256) ((unsigned int*)img2b)[i] = 0u;
    for (int i = t; i < 400; i += 256) wsc[i] = conv1_w[i];
    if (t < 16) bsc[t] = conv1_b[t];
    __syncthreads();
    for (int i = t; i < 784; i += 256)
        xs[(i / 28 + 1) * 30 + (i % 28) + 1] = x[b * 784 + i];
    __syncthreads();

    // ---- phase 1: deform1 -> img2 (padded by 2) ----
    for (int p = t; p < 784; p += 256) {
        int h = p / 28, w = p % 28;
        float off[2];
        int flat0 = h * 56 + w * 2;
#pragma unroll
        for (int k = 0; k < 2; ++k) {
            int flat = flat0 + k;
            int c = flat / 784;
            int r = flat % 784;
            int hh = r / 28, ww = r % 28;
            float s = 0.f;
#pragma unroll
            for (int dy = 0; dy < 3; ++dy)
#pragma unroll
                for (int dx = 0; dx < 3; ++dx)
                    s += off1_w[c * 9 + dy * 3 + dx] * xs[(hh + dy) * 30 + ww + dx];
            off[k] = s;
        }
        float cy = fminf(fmaxf((float)h + off[0], 0.f), 27.f);
        float cx = fminf(fmaxf((float)w + off[1], 0.f), 27.f);
        float y0f = floorf(cy), x0f = floorf(cx);
        int y0 = (int)y0f, x0 = (int)x0f;
        int y1 = (int)ceilf(cy), x1 = (int)ceilf(cx);
        float ty = cy - y0f, tx = cx - x0f;
        float vlt = xs[(y0 + 1) * 30 + x0 + 1], vrt = xs[(y0 + 1) * 30 + x1 + 1];
        float vlb = xs[(y1 + 1) * 30 + x0 + 1], vrb = xs[(y1 + 1) * 30 + x1 + 1];
        float vt = vlt + (vrt - vlt) * tx;
        float vb = vlb + (vrb - vlb) * tx;
        img2[(h + 2) * 32 + (w + 2)] = vt + (vb - vt) * ty;
    }
    __syncthreads();

    // ---- phase 2: conv1 5x5 p2 + relu + pool -> imgb (bf16 ch-last) ----
    {
        int oc = t & 15;
        float wv[25];
#pragma unroll
        for (int q = 0; q < 25; ++q) wv[q] = wsc[oc * 25 + q];
        float bv = bsc[oc];
        for (int o = t; o < 1568; o += 256) {
            int r = o >> 4;  // 0..97
            int i = r / 7, jp = r % 7;
            float s_[2][4];
#pragma unroll
            for (int py = 0; py < 2; ++py)
#pragma unroll
                for (int cx = 0; cx < 4; ++cx) s_[py][cx] = bv;
#pragma unroll
            for (int q = 0; q < 6; ++q) {  // stream patch rows
                const float4* rp = (const float4*)&img2[(2 * i + q) * 32 + 4 * jp];
                float4 ra = rp[0], rb = rp[1];
                float row[8] = {ra.x, ra.y, ra.z, ra.w, rb.x, rb.y, rb.z, rb.w};
#pragma unroll
                for (int py = 0; py < 2; ++py) {
                    int dy = q - py;
                    if (dy >= 0 && dy < 5) {
#pragma unroll
                        for (int cx = 0; cx < 4; ++cx)
#pragma unroll
                            for (int dx = 0; dx < 5; ++dx)
                                s_[py][cx] += wv[dy * 5 + dx] * row[cx + dx];
                    }
                }
            }
            float m0 = fmaxf(fmaxf(s_[0][0], s_[0][1]), fmaxf(s_[1][0], s_[1][1]));
            float m1 = fmaxf(fmaxf(s_[0][2], s_[0][3]), fmaxf(s_[1][2], s_[1][3]));
            m0 = fmaxf(m0, 0.f);
            m1 = fmaxf(m1, 0.f);
            imgb[(i + 1) * 256 + (2 * jp + 1) * 16 + oc] = __float2bfloat16(m0);
            imgb[(i + 1) * 256 + (2 * jp + 2) * 16 + oc] = __float2bfloat16(m1);
        }
    }
    __syncthreads();

    int wv_ = t >> 6, li = t & 63;
    int och = wv_ & 1, yh = wv_ >> 1;   // wave -> (oc half, row half)
    int nrows = yh ? 6 : 8;             // rows gy = yh*8 + y
    int lx = li & 15, lg = li >> 4;

    // ---- phase A: offset conv (32,14,14) via MFMA shift-GEMM -> offbuf ----
    {
        const bf16x8* wA = (const bf16x8*)wqo;
        bf16x8 afA[5];
#pragma unroll
        for (int sp = 0; sp < 5; ++sp)
            afA[sp] = wA[(sp * 32 + och * 16 + lx) * 4 + lg];
        int slA = lg >> 1, icsel = lg & 1;
        f32x4 acc[8];
#pragma unroll
        for (int y = 0; y < 8; ++y) acc[y] = (f32x4){0.f, 0.f, 0.f, 0.f};
        const bf16x8* ib = (const bf16x8*)imgb;
#pragma unroll
        for (int sp = 0; sp < 5; ++sp) {
            int s0 = 2 * sp + slA;
            int dy = s0 / 3, dx = s0 % 3;
            if (s0 >= 9) { dy = 0; dx = 0; }  // zero-weight pad step
            int base = dy * 32 + (lx + dx) * 2 + icsel;
#pragma unroll
            for (int y = 0; y < 8; ++y) {
                if (y < nrows) {
                    bf16x8 bfr = ib[base + (yh * 8 + y) * 32];
                    acc[y] = __builtin_amdgcn_mfma_f32_16x16x32_bf16(afA[sp], bfr, acc[y], 0, 0, 0);
                }
            }
        }
        if (lx < 14) {
#pragma unroll
            for (int y = 0; y < 8; ++y) {
                if (y < nrows) {
                    int yy = yh * 8 + y;
#pragma unroll
                    for (int r = 0; r < 4; ++r) {
                        int oc = och * 16 + lg * 4 + r;
                        offbuf[oc * 196 + yy * 14 + lx] = (_Float16)acc[y][r];
                    }
                }
            }
        }
    }
    __syncthreads();

    // ---- phase B: raw-reshape remap + bilinear -> img2b (c-inner for banks) ----
    for (int o = t; o < 3136; o += 256) {
        int c = o & 15, rem = o >> 4;  // 16 lanes share (h,w), differ in c
        int h = rem / 14, w = rem % 14;
        int flat0 = c * 392 + h * 28 + w * 2;
        float offy = (float)offbuf[flat0];
        float offx = (float)offbuf[flat0 + 1];
        float cy = fminf(fmaxf((float)h + offy, 0.f), 13.f);
        float cx = fminf(fmaxf((float)w + offx, 0.f), 13.f);
        float y0f = floorf(cy), x0f = floorf(cx);
        int y0 = (int)y0f, x0 = (int)x0f;
        int y1 = (int)ceilf(cy), x1 = (int)ceilf(cx);
        float ty = cy - y0f, tx = cx - x0f;
        float vlt = __bfloat162float(imgb[(y0 + 1) * 256 + (x0 + 1) * 16 + c]);
        float vrt = __bfloat162float(imgb[(y0 + 1) * 256 + (x1 + 1) * 16 + c]);
        float vlb = __bfloat162float(imgb[(y1 + 1) * 256 + (x0 + 1) * 16 + c]);
        float vrb = __bfloat162float(imgb[(y1 + 1) * 256 + (x1 + 1) * 16 + c]);
        float vt = vlt + (vrt - vlt) * tx;
        float vb = vlb + (vrb - vlb) * tx;
        img2b[((h + 2) * 20 + (w + 2)) * 16 + c] = __float2bfloat16(vt + (vb - vt) * ty);
    }
    __syncthreads();

    // ---- phase C: conv2 MFMA shift-GEMM + bias + relu + fused maxpool -> pl ----
    {
        const bf16x8* wB = (const bf16x8*)wq2;
        bf16x8 af[13];
#pragma unroll
        for (int sp = 0; sp < 13; ++sp)
            af[sp] = wB[(sp * 32 + och * 16 + lx) * 4 + lg];
        int sl = lg >> 1, icg = lg & 1;
        float bias_r[4];
#pragma unroll
        for (int r = 0; r < 4; ++r) bias_r[r] = conv2_b[och * 16 + lg * 4 + r];
        f32x4 acc[8];
#pragma unroll
        for (int y = 0; y < 8; ++y) acc[y] = (f32x4){0.f, 0.f, 0.f, 0.f};
        const bf16x8* ib2 = (const bf16x8*)img2b;
#pragma unroll
        for (int sp = 0; sp < 13; ++sp) {
            int s0 = 2 * sp + sl;
            int dy = s0 / 5, dx = s0 % 5;
            if (s0 >= 25) { dy = 0; dx = 0; }
            int base = (lx + dx) * 2 + icg;
#pragma unroll
            for (int y = 0; y < 8; ++y) {
                if (y < nrows) {
                    bf16x8 bfr = ib2[base + (yh * 8 + y + dy) * 40];
                    acc[y] = __builtin_amdgcn_mfma_f32_16x16x32_bf16(af[sp], bfr, acc[y], 0, 0, 0);
                }
            }
        }
        __syncthreads();  // offbuf (s5) dead; pl overlays it
        int npool = yh ? 3 : 4;
#pragma unroll
        for (int u = 0; u < 4; ++u) {
            if (u < npool) {
                int i = yh * 4 + u;
#pragma unroll
                for (int r = 0; r < 4; ++r) {
                    int oc = och * 16 + lg * 4 + r;
                    float v = fmaxf(fmaxf(acc[2 * u][r], acc[2 * u + 1][r]) + bias_r[r], 0.f);
                    float p = __shfl_xor(v, 1);
                    float m = fmaxf(v, p);
                    if (((lx & 1) == 0) && lx < 14)
                        pl[oc * 49 + i * 7 + (lx >> 1)] = m;
                }
            }
        }
    }
    __syncthreads();

    // ---- phase E: FC 1568->10 (float4 loads) ----
    float facc[10];
#pragma unroll
    for (int o = 0; o < 10; ++o) facc[o] = 0.f;
#pragma unroll
    for (int it = 0; it < 2; ++it) {
        int k = t * 4 + it * 1024;
        if (k < 1568) {
            float4 v = *(const float4*)&pl[k];
#pragma unroll
            for (int o = 0; o < 10; ++o) {
                float4 w4 = *(const float4*)&fc_w[o * 1568 + k];
                facc[o] += v.x * w4.x + v.y * w4.y + v.z * w4.z + v.w * w4.w;
            }
        }
    }
#pragma unroll
    for (int o = 0; o < 10; ++o) {
        float s = facc[o];
#pragma unroll
        for (int m = 32; m > 0; m >>= 1) s += __shfl_xor(s, m);
        if (li == 0) wredp[o * 4 + wv_] = s;
    }
    __syncthreads();
    if (t < 10)
        out[b * 10 + t] = fc_b[t] + wredp[t * 4] + wredp[t * 4 + 1] + wredp[t * 4 + 2] + wredp[t * 4 + 3];
}

extern "C" void kernel_launch(void* const* d_in, const int* in_sizes, int n_in,
                              void* d_out, int out_size, void* d_ws, size_t ws_size,
                              hipStream_t stream) {
    const float* x       = (const float*)d_in[0];
    const float* off1_w  = (const float*)d_in[1];
    const float* conv1_w = (const float*)d_in[2];
    const float* conv1_b = (const float*)d_in[3];
    const float* off2_w  = (const float*)d_in[4];
    const float* conv2_w = (const float*)d_in[5];
    const float* conv2_b = (const float*)d_in[6];
    const float* fc_w    = (const float*)d_in[7];
    const float* fc_b    = (const float*)d_in[8];
    float* out = (float*)d_out;

    char* ws = (char*)d_ws;
    __hip_bfloat16* wqo = (__hip_bfloat16*)ws;             // 5120 bf16  = 10240 B
    __hip_bfloat16* wq2 = (__hip_bfloat16*)(ws + 10240);   // 13312 bf16 = 26624 B

    k_prep<<<72, 256, 0, stream>>>(off2_w, conv2_w, wqo, wq2);
    k_net<<<B_IMG, 256, 0, stream>>>(x, off1_w, conv1_w, conv1_b, wqo, wq2,
                                     conv2_b, fc_w, fc_b, out);
}

// Round 9
// 61.258 us; speedup vs baseline: 11.6407x; 1.1440x over previous
//
#include <hip/hip_runtime.h>
#include <hip/hip_bf16.h>

// Fully-fused deform-conv MNIST net. B=2048, one block per image.
// LDS = 32768 B. All three convs on MFMA. Pool fused into epilogues.
//   s5    : xs|img2bf (ph0-2) -> offbuf (phA-B) -> pl+wred (phC-E)
//   imgb  : bf16 ch-last h1 (ph2-B)
//   img2b : bf16 ch-last d2 (phB-C)

#define B_IMG 2048

typedef short bf16x8 __attribute__((ext_vector_type(8)));
typedef float f32x4 __attribute__((ext_vector_type(4)));

// wqo  [5][32][32]  : off2_w (32,16,3,3) -> k=sl*16+ic, s=2*sp+sl, s>=9 zero
// wq2  [13][32][32] : conv2_w (32,16,5,5) -> s>=25 zero
// wqc1 [16][32]     : conv1_w (16,1,5,5)  -> k=tap, k>=25 zero
__global__ __launch_bounds__(256) void k_prep(const float* __restrict__ w_off2,
                                              const float* __restrict__ w_c2,
                                              const float* __restrict__ w_c1,
                                              __hip_bfloat16* __restrict__ wqo,
                                              __hip_bfloat16* __restrict__ wq2,
                                              __hip_bfloat16* __restrict__ wqc1) {
    int e = blockIdx.x * 256 + threadIdx.x;
    if (e < 5120) {
        int sp = e >> 10, rem = e & 1023, oc = rem >> 5, k = rem & 31;
        int sl = k >> 4, ic = k & 15, s = 2 * sp + sl;
        wqo[e] = __float2bfloat16(s < 9 ? w_off2[(oc * 16 + ic) * 9 + s] : 0.f);
    } else if (e < 18432) {
        int e2 = e - 5120;
        int sp = e2 >> 10, rem = e2 & 1023, oc = rem >> 5, k = rem & 31;
        int sl = k >> 4, ic = k & 15, s = 2 * sp + sl;
        wq2[e2] = __float2bfloat16(s < 25 ? w_c2[(oc * 16 + ic) * 25 + s] : 0.f);
    } else if (e < 18944) {
        int e3 = e - 18432;
        int oc = e3 >> 5, k = e3 & 31;
        wqc1[e3] = __float2bfloat16(k < 25 ? w_c1[oc * 25 + k] : 0.f);
    }
}

__global__ __launch_bounds__(256, 4) void k_net(const float* __restrict__ x,        // (B,1,28,28)
                                                const float* __restrict__ off1_w,   // (2,1,3,3)
                                                const __hip_bfloat16* __restrict__ wqc1,
                                                const float* __restrict__ conv1_b,  // (16)
                                                const __hip_bfloat16* __restrict__ wqo,
                                                const __hip_bfloat16* __restrict__ wq2,
                                                const float* __restrict__ conv2_b,  // (32)
                                                const float* __restrict__ fc_w,     // (10,1568)
                                                const float* __restrict__ fc_b,     // (10)
                                                float* __restrict__ out) {          // (B,10)
    __shared__ __align__(16) char s5[12544];                      // multi-use scratch
    __shared__ __align__(16) __hip_bfloat16 imgb[17 * 16 * 16];   // 8704 B
    __shared__ __align__(16) __hip_bfloat16 img2b[18 * 20 * 16];  // 11520 B

    float* xs = (float*)s5;                       // [30][30] pad1, 3600 B
    __hip_bfloat16* img2bf = (__hip_bfloat16*)(s5 + 3600);  // [32][36] pad2 bf16, 2304 B
    _Float16* offbuf = (_Float16*)s5;             // phase A-B, 12544 B
    float* pl    = (float*)s5;                    // phase C-E, 6272 B (pooled 32x7x7)
    float* wredp = (float*)(s5 + 6272);           // phase E, 160 B

    int b = blockIdx.x, t = threadIdx.x;

    // ---- phase 0: zero pads, stage input ----
    for (int i = t; i < 900; i += 256) xs[i] = 0.f;
    for (int i = t; i < 576; i += 256) ((unsigned int*)img2bf)[i] = 0u;
    for (int i = t; i < 2176; i += 256) ((unsigned int*)imgb)[i] = 0u;
    for (int i = t; i < 2880; i += 256) ((unsigned int*)img2b)[i] = 0u;
    __syncthreads();
    for (int i = t; i < 784; i += 256)
        xs[(i / 28 + 1) * 30 + (i % 28) + 1] = x[b * 784 + i];
    __syncthreads();

    // ---- phase 1: deform1 -> img2bf (bf16, padded by 2, 36-wide) ----
    for (int p = t; p < 784; p += 256) {
        int h = p / 28, w = p % 28;
        float off[2];
        int flat0 = h * 56 + w * 2;
#pragma unroll
        for (int k = 0; k < 2; ++k) {
            int flat = flat0 + k;
            int c = flat / 784;
            int r = flat % 784;
            int hh = r / 28, ww = r % 28;
            float s = 0.f;
#pragma unroll
            for (int dy = 0; dy < 3; ++dy)
#pragma unroll
                for (int dx = 0; dx < 3; ++dx)
                    s += off1_w[c * 9 + dy * 3 + dx] * xs[(hh + dy) * 30 + ww + dx];
            off[k] = s;
        }
        float cy = fminf(fmaxf((float)h + off[0], 0.f), 27.f);
        float cx = fminf(fmaxf((float)w + off[1], 0.f), 27.f);
        float y0f = floorf(cy), x0f = floorf(cx);
        int y0 = (int)y0f, x0 = (int)x0f;
        int y1 = (int)ceilf(cy), x1 = (int)ceilf(cx);
        float ty = cy - y0f, tx = cx - x0f;
        float vlt = xs[(y0 + 1) * 30 + x0 + 1], vrt = xs[(y0 + 1) * 30 + x1 + 1];
        float vlb = xs[(y1 + 1) * 30 + x0 + 1], vrb = xs[(y1 + 1) * 30 + x1 + 1];
        float vt = vlt + (vrt - vlt) * tx;
        float vb = vlb + (vrb - vlb) * tx;
        img2bf[(h + 2) * 36 + (w + 2)] = __float2bfloat16(vt + (vb - vt) * ty);
    }
    __syncthreads();

    int wv_ = t >> 6, li = t & 63;
    int lx = li & 15, lg = li >> 4;

    // ---- phase 2: conv1 via MFMA (M=16oc, N=pos, K=32 taps) + relu + pool -> imgb ----
    {
        const bf16x8* wc1v = (const bf16x8*)wqc1;
        bf16x8 af1 = wc1v[lx * 4 + lg];  // A: row=oc=lx, k-slice=lg*8
        float b4[4];
#pragma unroll
        for (int r = 0; r < 4; ++r) b4[r] = conv1_b[lg * 4 + r];
        int ypstart = (wv_ < 2) ? wv_ * 4 : 8 + (wv_ - 2) * 3;
        int ypcnt = (wv_ < 2) ? 4 : 3;
        const unsigned short* ib28 = (const unsigned short*)img2bf;
        for (int u = 0; u < 4; ++u) {
            if (u < ypcnt) {
                int yp = ypstart + u;
#pragma unroll
                for (int xh = 0; xh < 2; ++xh) {
                    int xp = xh * 16 + lx;  // conv position x (B col = lx)
                    f32x4 a0 = (f32x4){0.f, 0.f, 0.f, 0.f};
                    f32x4 a1 = (f32x4){0.f, 0.f, 0.f, 0.f};
#pragma unroll
                    for (int yy = 0; yy < 2; ++yy) {
                        int y = 2 * yp + yy;
                        unsigned short uu[8];
#pragma unroll
                        for (int j = 0; j < 8; ++j) {
                            int tt = 8 * lg + j;     // tap index (k)
                            int dyq = tt / 5;
                            int dxq = tt - 5 * dyq;
                            unsigned short v = 0;
                            if (tt < 25) v = ib28[(y + dyq) * 36 + xp + dxq];
                            uu[j] = v;
                        }
                        bf16x8 bq = {(short)uu[0], (short)uu[1], (short)uu[2], (short)uu[3],
                                     (short)uu[4], (short)uu[5], (short)uu[6], (short)uu[7]};
                        if (yy == 0)
                            a0 = __builtin_amdgcn_mfma_f32_16x16x32_bf16(af1, bq, a0, 0, 0, 0);
                        else
                            a1 = __builtin_amdgcn_mfma_f32_16x16x32_bf16(af1, bq, a1, 0, 0, 0);
                    }
#pragma unroll
                    for (int r = 0; r < 4; ++r) {
                        float v = fmaxf(fmaxf(a0[r], a1[r]) + b4[r], 0.f);
                        float p = __shfl_xor(v, 1);
                        float m = fmaxf(v, p);
                        if (((xp & 1) == 0) && xp < 28) {
                            int oc = lg * 4 + r;
                            imgb[(yp + 1) * 256 + ((xp >> 1) + 1) * 16 + oc] = __float2bfloat16(m);
                        }
                    }
                }
            }
        }
    }
    __syncthreads();

    int och = wv_ & 1, yh = wv_ >> 1;   // wave -> (oc half, row half)
    int nrows = yh ? 6 : 8;             // rows gy = yh*8 + y

    // ---- phase A: offset conv (32,14,14) via MFMA shift-GEMM -> offbuf ----
    {
        const bf16x8* wA = (const bf16x8*)wqo;
        bf16x8 afA[5];
#pragma unroll
        for (int sp = 0; sp < 5; ++sp)
            afA[sp] = wA[(sp * 32 + och * 16 + lx) * 4 + lg];
        int slA = lg >> 1, icsel = lg & 1;
        f32x4 acc[8];
#pragma unroll
        for (int y = 0; y < 8; ++y) acc[y] = (f32x4){0.f, 0.f, 0.f, 0.f};
        const bf16x8* ib = (const bf16x8*)imgb;
#pragma unroll
        for (int sp = 0; sp < 5; ++sp) {
            int s0 = 2 * sp + slA;
            int dy = s0 / 3, dx = s0 % 3;
            if (s0 >= 9) { dy = 0; dx = 0; }  // zero-weight pad step
            int base = dy * 32 + (lx + dx) * 2 + icsel;
#pragma unroll
            for (int y = 0; y < 8; ++y) {
                if (y < nrows) {
                    bf16x8 bfr = ib[base + (yh * 8 + y) * 32];
                    acc[y] = __builtin_amdgcn_mfma_f32_16x16x32_bf16(afA[sp], bfr, acc[y], 0, 0, 0);
                }
            }
        }
        if (lx < 14) {
#pragma unroll
            for (int y = 0; y < 8; ++y) {
                if (y < nrows) {
                    int yy = yh * 8 + y;
#pragma unroll
                    for (int r = 0; r < 4; ++r) {
                        int oc = och * 16 + lg * 4 + r;
                        offbuf[oc * 196 + yy * 14 + lx] = (_Float16)acc[y][r];
                    }
                }
            }
        }
    }
    __syncthreads();

    // ---- phase B: raw-reshape remap + bilinear -> img2b (c-inner for banks) ----
    for (int o = t; o < 3136; o += 256) {
        int c = o & 15, rem = o >> 4;  // 16 lanes share (h,w), differ in c
        int h = rem / 14, w = rem % 14;
        int flat0 = c * 392 + h * 28 + w * 2;
        float offy = (float)offbuf[flat0];
        float offx = (float)offbuf[flat0 + 1];
        float cy = fminf(fmaxf((float)h + offy, 0.f), 13.f);
        float cx = fminf(fmaxf((float)w + offx, 0.f), 13.f);
        float y0f = floorf(cy), x0f = floorf(cx);
        int y0 = (int)y0f, x0 = (int)x0f;
        int y1 = (int)ceilf(cy), x1 = (int)ceilf(cx);
        float ty = cy - y0f, tx = cx - x0f;
        float vlt = __bfloat162float(imgb[(y0 + 1) * 256 + (x0 + 1) * 16 + c]);
        float vrt = __bfloat162float(imgb[(y0 + 1) * 256 + (x1 + 1) * 16 + c]);
        float vlb = __bfloat162float(imgb[(y1 + 1) * 256 + (x0 + 1) * 16 + c]);
        float vrb = __bfloat162float(imgb[(y1 + 1) * 256 + (x1 + 1) * 16 + c]);
        float vt = vlt + (vrt - vlt) * tx;
        float vb = vlb + (vrb - vlb) * tx;
        img2b[((h + 2) * 20 + (w + 2)) * 16 + c] = __float2bfloat16(vt + (vb - vt) * ty);
    }
    __syncthreads();

    // ---- phase C: conv2 MFMA shift-GEMM + bias + relu + fused maxpool -> pl ----
    {
        const bf16x8* wB = (const bf16x8*)wq2;
        bf16x8 af[13];
#pragma unroll
        for (int sp = 0; sp < 13; ++sp)
            af[sp] = wB[(sp * 32 + och * 16 + lx) * 4 + lg];
        int sl = lg >> 1, icg = lg & 1;
        float bias_r[4];
#pragma unroll
        for (int r = 0; r < 4; ++r) bias_r[r] = conv2_b[och * 16 + lg * 4 + r];
        f32x4 acc[8];
#pragma unroll
        for (int y = 0; y < 8; ++y) acc[y] = (f32x4){0.f, 0.f, 0.f, 0.f};
        const bf16x8* ib2 = (const bf16x8*)img2b;
#pragma unroll
        for (int sp = 0; sp < 13; ++sp) {
            int s0 = 2 * sp + sl;
            int dy = s0 / 5, dx = s0 % 5;
            if (s0 >= 25) { dy = 0; dx = 0; }
            int base = (lx + dx) * 2 + icg;
#pragma unroll
            for (int y = 0; y < 8; ++y) {
                if (y < nrows) {
                    bf16x8 bfr = ib2[base + (yh * 8 + y + dy) * 40];
                    acc[y] = __builtin_amdgcn_mfma_f32_16x16x32_bf16(af[sp], bfr, acc[y], 0, 0, 0);
                }
            }
        }
        __syncthreads();  // offbuf (s5) dead; pl overlays it
        int npool = yh ? 3 : 4;
#pragma unroll
        for (int u = 0; u < 4; ++u) {
            if (u < npool) {
                int i = yh * 4 + u;
#pragma unroll
                for (int r = 0; r < 4; ++r) {
                    int oc = och * 16 + lg * 4 + r;
                    float v = fmaxf(fmaxf(acc[2 * u][r], acc[2 * u + 1][r]) + bias_r[r], 0.f);
                    float p = __shfl_xor(v, 1);
                    float m = fmaxf(v, p);
                    if (((lx & 1) == 0) && lx < 14)
                        pl[oc * 49 + i * 7 + (lx >> 1)] = m;
                }
            }
        }
    }
    __syncthreads();

    // ---- phase E: FC 1568->10 (float4 loads) ----
    float facc[10];
#pragma unroll
    for (int o = 0; o < 10; ++o) facc[o] = 0.f;
#pragma unroll
    for (int it = 0; it < 2; ++it) {
        int k = t * 4 + it * 1024;
        if (k < 1568) {
            float4 v = *(const float4*)&pl[k];
#pragma unroll
            for (int o = 0; o < 10; ++o) {
                float4 w4 = *(const float4*)&fc_w[o * 1568 + k];
                facc[o] += v.x * w4.x + v.y * w4.y + v.z * w4.z + v.w * w4.w;
            }
        }
    }
#pragma unroll
    for (int o = 0; o < 10; ++o) {
        float s = facc[o];
#pragma unroll
        for (int m = 32; m > 0; m >>= 1) s += __shfl_xor(s, m);
        if (li == 0) wredp[o * 4 + wv_] = s;
    }
    __syncthreads();
    if (t < 10)
        out[b * 10 + t] = fc_b[t] + wredp[t * 4] + wredp[t * 4 + 1] + wredp[t * 4 + 2] + wredp[t * 4 + 3];
}

extern "C" void kernel_launch(void* const* d_in, const int* in_sizes, int n_in,
                              void* d_out, int out_size, void* d_ws, size_t ws_size,
                              hipStream_t stream) {
    const float* x       = (const float*)d_in[0];
    const float* off1_w  = (const float*)d_in[1];
    const float* conv1_w = (const float*)d_in[2];
    const float* conv1_b = (const float*)d_in[3];
    const float* off2_w  = (const float*)d_in[4];
    const float* conv2_w = (const float*)d_in[5];
    const float* conv2_b = (const float*)d_in[6];
    const float* fc_w    = (const float*)d_in[7];
    const float* fc_b    = (const float*)d_in[8];
    float* out = (float*)d_out;

    char* ws = (char*)d_ws;
    __hip_bfloat16* wqo  = (__hip_bfloat16*)ws;             // 5120 bf16  = 10240 B
    __hip_bfloat16* wq2  = (__hip_bfloat16*)(ws + 10240);   // 13312 bf16 = 26624 B
    __hip_bfloat16* wqc1 = (__hip_bfloat16*)(ws + 36864);   // 512 bf16   = 1024 B

    k_prep<<<74, 256, 0, stream>>>(off2_w, conv2_w, conv1_w, wqo, wq2, wqc1);
    k_net<<<B_IMG, 256, 0, stream>>>(x, off1_w, wqc1, conv1_b, wqo, wq2,
                                     conv2_b, fc_w, fc_b, out);
}

// Round 11
// 60.525 us; speedup vs baseline: 11.7817x; 1.0121x over previous
//
#include <hip/hip_runtime.h>
#include <hip/hip_bf16.h>

// Fully-fused deform-conv MNIST net. B=2048, one block per image.
// LDS = 32256 B (-> 5 blocks/CU). All three convs on MFMA.
//   s5    : xs|img2bf (ph0-1) -> offbuf (phA-B) -> pl+wred (phC-E)
//   imgb  : bf16 ch-last h1 [16][16][16] (ph2-B)
//   img2b : bf16 ch-last d2 [18][20][16] (phB-C)

#define B_IMG 2048

typedef short bf16x8 __attribute__((ext_vector_type(8)));
typedef float f32x4 __attribute__((ext_vector_type(4)));

// wqo  [5][32][32]  : off2_w (32,16,3,3) -> k=sl*16+ic, s=2*sp+sl, s>=9 zero
// wq2  [13][32][32] : conv2_w (32,16,5,5) -> s>=25 zero
// wqc1 [16][32]     : conv1_w (16,1,5,5)  -> k=tap, k>=25 zero
__global__ __launch_bounds__(256) void k_prep(const float* __restrict__ w_off2,
                                              const float* __restrict__ w_c2,
                                              const float* __restrict__ w_c1,
                                              __hip_bfloat16* __restrict__ wqo,
                                              __hip_bfloat16* __restrict__ wq2,
                                              __hip_bfloat16* __restrict__ wqc1) {
    int e = blockIdx.x * 256 + threadIdx.x;
    if (e < 5120) {
        int sp = e >> 10, rem = e & 1023, oc = rem >> 5, k = rem & 31;
        int sl = k >> 4, ic = k & 15, s = 2 * sp + sl;
        wqo[e] = __float2bfloat16(s < 9 ? w_off2[(oc * 16 + ic) * 9 + s] : 0.f);
    } else if (e < 18432) {
        int e2 = e - 5120;
        int sp = e2 >> 10, rem = e2 & 1023, oc = rem >> 5, k = rem & 31;
        int sl = k >> 4, ic = k & 15, s = 2 * sp + sl;
        wq2[e2] = __float2bfloat16(s < 25 ? w_c2[(oc * 16 + ic) * 25 + s] : 0.f);
    } else if (e < 18944) {
        int e3 = e - 18432;
        int oc = e3 >> 5, k = e3 & 31;
        wqc1[e3] = __float2bfloat16(k < 25 ? w_c1[oc * 25 + k] : 0.f);
    }
}

__global__ __launch_bounds__(256, 4) void k_net(const float* __restrict__ x,        // (B,1,28,28)
                                                const float* __restrict__ off1_w,   // (2,1,3,3)
                                                const __hip_bfloat16* __restrict__ wqc1,
                                                const float* __restrict__ conv1_b,  // (16)
                                                const __hip_bfloat16* __restrict__ wqo,
                                                const __hip_bfloat16* __restrict__ wq2,
                                                const float* __restrict__ conv2_b,  // (32)
                                                const float* __restrict__ fc_w,     // (10,1568)
                                                const float* __restrict__ fc_b,     // (10)
                                                float* __restrict__ out) {          // (B,10)
    __shared__ __align__(16) char s5[12544];                      // multi-use scratch
    __shared__ __align__(16) __hip_bfloat16 imgb[16 * 16 * 16];   // 8192 B
    __shared__ __align__(16) __hip_bfloat16 img2b[18 * 20 * 16];  // 11520 B

    float* xs = (float*)s5;                       // [30][30] pad1, 3600 B
    __hip_bfloat16* img2bf = (__hip_bfloat16*)(s5 + 3600);  // [32][36] pad2 bf16, 2304 B
    _Float16* offbuf = (_Float16*)s5;             // phase A-B, 12544 B
    float* pl    = (float*)s5;                    // phase C-E, 6272 B (pooled 32x7x7)
    float* wredp = (float*)(s5 + 6272);           // phase E, 160 B

    int b = blockIdx.x, t = threadIdx.x;

    // ---- phase 0: zero pads, stage input ----
    for (int i = t; i < 900; i += 256) xs[i] = 0.f;
    for (int i = t; i < 576; i += 256) ((unsigned int*)img2bf)[i] = 0u;
    for (int i = t; i < 2048; i += 256) ((unsigned int*)imgb)[i] = 0u;
    for (int i = t; i < 2880; i += 256) ((unsigned int*)img2b)[i] = 0u;
    __syncthreads();
    for (int i = t; i < 784; i += 256)
        xs[(i / 28 + 1) * 30 + (i % 28) + 1] = x[b * 784 + i];
    __syncthreads();

    // ---- phase 1: deform1 -> img2bf (bf16, padded by 2, 36-wide) ----
    for (int p = t; p < 784; p += 256) {
        int h = p / 28, w = p % 28;
        float off[2];
        int flat0 = h * 56 + w * 2;
#pragma unroll
        for (int k = 0; k < 2; ++k) {
            int flat = flat0 + k;
            int c = flat / 784;
            int r = flat % 784;
            int hh = r / 28, ww = r % 28;
            float s = 0.f;
#pragma unroll
            for (int dy = 0; dy < 3; ++dy)
#pragma unroll
                for (int dx = 0; dx < 3; ++dx)
                    s += off1_w[c * 9 + dy * 3 + dx] * xs[(hh + dy) * 30 + ww + dx];
            off[k] = s;
        }
        float cy = fminf(fmaxf((float)h + off[0], 0.f), 27.f);
        float cx = fminf(fmaxf((float)w + off[1], 0.f), 27.f);
        float y0f = floorf(cy), x0f = floorf(cx);
        int y0 = (int)y0f, x0 = (int)x0f;
        int y1 = (int)ceilf(cy), x1 = (int)ceilf(cx);
        float ty = cy - y0f, tx = cx - x0f;
        float vlt = xs[(y0 + 1) * 30 + x0 + 1], vrt = xs[(y0 + 1) * 30 + x1 + 1];
        float vlb = xs[(y1 + 1) * 30 + x0 + 1], vrb = xs[(y1 + 1) * 30 + x1 + 1];
        float vt = vlt + (vrt - vlt) * tx;
        float vb = vlb + (vrb - vlb) * tx;
        img2bf[(h + 2) * 36 + (w + 2)] = __float2bfloat16(vt + (vb - vt) * ty);
    }
    __syncthreads();

    int wv_ = t >> 6, li = t & 63;
    int lx = li & 15, lg = li >> 4;

    // ---- phase 2: conv1 via MFMA (M=16oc, N=pos, K=32 taps) + relu + pool -> imgb ----
    {
        const bf16x8* wc1v = (const bf16x8*)wqc1;
        bf16x8 af1 = wc1v[lx * 4 + lg];  // A: row=oc=lx, k-slice=lg*8
        float b4[4];
#pragma unroll
        for (int r = 0; r < 4; ++r) b4[r] = conv1_b[lg * 4 + r];
        // hoisted tap decode: 8 offsets + valid masks (lg fixed per thread)
        int toff[8];
        unsigned short msk[8];
#pragma unroll
        for (int j = 0; j < 8; ++j) {
            int tt = 8 * lg + j;
            int dyq = tt / 5, dxq = tt - 5 * dyq;
            toff[j] = (tt < 25) ? (dyq * 36 + dxq) : 0;
            msk[j] = (tt < 25) ? 0xFFFFu : 0u;
        }
        int ypstart = (wv_ < 2) ? wv_ * 4 : 8 + (wv_ - 2) * 3;
        int ypcnt = (wv_ < 2) ? 4 : 3;
        const unsigned short* ib28 = (const unsigned short*)img2bf;
        for (int u = 0; u < 4; ++u) {
            if (u < ypcnt) {
                int yp = ypstart + u;
#pragma unroll
                for (int xh = 0; xh < 2; ++xh) {
                    int xp = xh * 16 + lx;  // conv position x (B col = lx)
                    f32x4 a0 = (f32x4){0.f, 0.f, 0.f, 0.f};
                    f32x4 a1 = (f32x4){0.f, 0.f, 0.f, 0.f};
#pragma unroll
                    for (int yy = 0; yy < 2; ++yy) {
                        int base16 = (2 * yp + yy) * 36 + xp;
                        unsigned short uu[8];
#pragma unroll
                        for (int j = 0; j < 8; ++j)
                            uu[j] = (unsigned short)(ib28[base16 + toff[j]] & msk[j]);
                        bf16x8 bq = {(short)uu[0], (short)uu[1], (short)uu[2], (short)uu[3],
                                     (short)uu[4], (short)uu[5], (short)uu[6], (short)uu[7]};
                        if (yy == 0)
                            a0 = __builtin_amdgcn_mfma_f32_16x16x32_bf16(af1, bq, a0, 0, 0, 0);
                        else
                            a1 = __builtin_amdgcn_mfma_f32_16x16x32_bf16(af1, bq, a1, 0, 0, 0);
                    }
#pragma unroll
                    for (int r = 0; r < 4; ++r) {
                        float v = fmaxf(fmaxf(a0[r], a1[r]) + b4[r], 0.f);
                        float p = __shfl_xor(v, 1);
                        float m = fmaxf(v, p);
                        if (((xp & 1) == 0) && xp < 28) {
                            int oc = lg * 4 + r;
                            imgb[(yp + 1) * 256 + ((xp >> 1) + 1) * 16 + oc] = __float2bfloat16(m);
                        }
                    }
                }
            }
        }
    }
    __syncthreads();

    int och = wv_ & 1, yh = wv_ >> 1;   // wave -> (oc half, row half)
    int nrows = yh ? 6 : 8;             // rows gy = yh*8 + y

    // ---- phase A: offset conv (32,14,14) via MFMA shift-GEMM -> offbuf ----
    {
        const bf16x8* wA = (const bf16x8*)wqo;
        bf16x8 afA[5];
#pragma unroll
        for (int sp = 0; sp < 5; ++sp)
            afA[sp] = wA[(sp * 32 + och * 16 + lx) * 4 + lg];
        int slA = lg >> 1, icsel = lg & 1;
        f32x4 acc[8];
#pragma unroll
        for (int y = 0; y < 8; ++y) acc[y] = (f32x4){0.f, 0.f, 0.f, 0.f};
        const bf16x8* ib = (const bf16x8*)imgb;
#pragma unroll
        for (int sp = 0; sp < 5; ++sp) {
            int s0 = 2 * sp + slA;
            int dy = s0 / 3, dx = s0 % 3;
            if (s0 >= 9) { dy = 0; dx = 0; }  // zero-weight pad step
            int base = dy * 32 + (lx + dx) * 2 + icsel;
#pragma unroll
            for (int y = 0; y < 8; ++y) {
                if (y < nrows) {
                    bf16x8 bfr = ib[base + (yh * 8 + y) * 32];
                    acc[y] = __builtin_amdgcn_mfma_f32_16x16x32_bf16(afA[sp], bfr, acc[y], 0, 0, 0);
                }
            }
        }
        if (lx < 14) {
#pragma unroll
            for (int y = 0; y < 8; ++y) {
                if (y < nrows) {
                    int yy = yh * 8 + y;
#pragma unroll
                    for (int r = 0; r < 4; ++r) {
                        int oc = och * 16 + lg * 4 + r;
                        offbuf[oc * 196 + yy * 14 + lx] = (_Float16)acc[y][r];
                    }
                }
            }
        }
    }
    __syncthreads();

    // ---- phase B: raw-reshape remap + bilinear -> img2b (c-inner for banks) ----
    for (int o = t; o < 3136; o += 256) {
        int c = o & 15, rem = o >> 4;  // 16 lanes share (h,w), differ in c
        int h = rem / 14, w = rem % 14;
        int pidx = c * 196 + h * 14 + w;  // = (c*392 + h*28 + w*2)/2
        unsigned int pr = ((const unsigned int*)offbuf)[pidx];
        unsigned short lo16 = (unsigned short)(pr & 0xFFFFu);
        unsigned short hi16 = (unsigned short)(pr >> 16);
        float offy = (float)(*(const _Float16*)&lo16);
        float offx = (float)(*(const _Float16*)&hi16);
        float cy = fminf(fmaxf((float)h + offy, 0.f), 13.f);
        float cx = fminf(fmaxf((float)w + offx, 0.f), 13.f);
        float y0f = floorf(cy), x0f = floorf(cx);
        int y0 = (int)y0f, x0 = (int)x0f;
        int y1 = (int)ceilf(cy), x1 = (int)ceilf(cx);
        float ty = cy - y0f, tx = cx - x0f;
        float vlt = __bfloat162float(imgb[(y0 + 1) * 256 + (x0 + 1) * 16 + c]);
        float vrt = __bfloat162float(imgb[(y0 + 1) * 256 + (x1 + 1) * 16 + c]);
        float vlb = __bfloat162float(imgb[(y1 + 1) * 256 + (x0 + 1) * 16 + c]);
        float vrb = __bfloat162float(imgb[(y1 + 1) * 256 + (x1 + 1) * 16 + c]);
        float vt = vlt + (vrt - vlt) * tx;
        float vb = vlb + (vrb - vlb) * tx;
        img2b[((h + 2) * 20 + (w + 2)) * 16 + c] = __float2bfloat16(vt + (vb - vt) * ty);
    }
    __syncthreads();

    // ---- phase C: conv2 MFMA shift-GEMM + bias + relu + fused maxpool -> pl ----
    {
        const bf16x8* wB = (const bf16x8*)wq2;
        bf16x8 af[13];
#pragma unroll
        for (int sp = 0; sp < 13; ++sp)
            af[sp] = wB[(sp * 32 + och * 16 + lx) * 4 + lg];
        int sl = lg >> 1, icg = lg & 1;
        float bias_r[4];
#pragma unroll
        for (int r = 0; r < 4; ++r) bias_r[r] = conv2_b[och * 16 + lg * 4 + r];
        f32x4 acc[8];
#pragma unroll
        for (int y = 0; y < 8; ++y) acc[y] = (f32x4){0.f, 0.f, 0.f, 0.f};
        const bf16x8* ib2 = (const bf16x8*)img2b;
#pragma unroll
        for (int sp = 0; sp < 13; ++sp) {
            int s0 = 2 * sp + sl;
            int dy = s0 / 5, dx = s0 % 5;
            if (s0 >= 25) { dy = 0; dx = 0; }
            int base = (lx + dx) * 2 + icg;
#pragma unroll
            for (int y = 0; y < 8; ++y) {
                if (y < nrows) {
                    bf16x8 bfr = ib2[base + (yh * 8 + y + dy) * 40];
                    acc[y] = __builtin_amdgcn_mfma_f32_16x16x32_bf16(af[sp], bfr, acc[y], 0, 0, 0);
                }
            }
        }
        __syncthreads();  // offbuf (s5) dead; pl overlays it
        int npool = yh ? 3 : 4;
#pragma unroll
        for (int u = 0; u < 4; ++u) {
            if (u < npool) {
                int i = yh * 4 + u;
#pragma unroll
                for (int r = 0; r < 4; ++r) {
                    int oc = och * 16 + lg * 4 + r;
                    float v = fmaxf(fmaxf(acc[2 * u][r], acc[2 * u + 1][r]) + bias_r[r], 0.f);
                    float p = __shfl_xor(v, 1);
                    float m = fmaxf(v, p);
                    if (((lx & 1) == 0) && lx < 14)
                        pl[oc * 49 + i * 7 + (lx >> 1)] = m;
                }
            }
        }
    }
    __syncthreads();

    // ---- phase E: FC 1568->10 (float4 loads) ----
    float facc[10];
#pragma unroll
    for (int o = 0; o < 10; ++o) facc[o] = 0.f;
#pragma unroll
    for (int it = 0; it < 2; ++it) {
        int k = t * 4 + it * 1024;
        if (k < 1568) {
            float4 v = *(const float4*)&pl[k];
#pragma unroll
            for (int o = 0; o < 10; ++o) {
                float4 w4 = *(const float4*)&fc_w[o * 1568 + k];
                facc[o] += v.x * w4.x + v.y * w4.y + v.z * w4.z + v.w * w4.w;
            }
        }
    }
#pragma unroll
    for (int o = 0; o < 10; ++o) {
        float s = facc[o];
#pragma unroll
        for (int m = 32; m > 0; m >>= 1) s += __shfl_xor(s, m);
        if (li == 0) wredp[o * 4 + wv_] = s;
    }
    __syncthreads();
    if (t < 10)
        out[b * 10 + t] = fc_b[t] + wredp[t * 4] + wredp[t * 4 + 1] + wredp[t * 4 + 2] + wredp[t * 4 + 3];
}

extern "C" void kernel_launch(void* const* d_in, const int* in_sizes, int n_in,
                              void* d_out, int out_size, void* d_ws, size_t ws_size,
                              hipStream_t stream) {
    const float* x       = (const float*)d_in[0];
    const float* off1_w  = (const float*)d_in[1];
    const float* conv1_w = (const float*)d_in[2];
    const float* conv1_b = (const float*)d_in[3];
    const float* off2_w  = (const float*)d_in[4];
    const float* conv2_w = (const float*)d_in[5];
    const float* conv2_b = (const float*)d_in[6];
    const float* fc_w    = (const float*)d_in[7];
    const float* fc_b    = (const float*)d_in[8];
    float* out = (float*)d_out;

    char* ws = (char*)d_ws;
    __hip_bfloat16* wqo  = (__hip_bfloat16*)ws;             // 5120 bf16  = 10240 B
    __hip_bfloat16* wq2  = (__hip_bfloat16*)(ws + 10240);   // 13312 bf16 = 26624 B
    __hip_bfloat16* wqc1 = (__hip_bfloat16*)(ws + 36864);   // 512 bf16   = 1024 B

    k_prep<<<74, 256, 0, stream>>>(off2_w, conv2_w, conv1_w, wqo, wq2, wqc1);
    k_net<<<B_IMG, 256, 0, stream>>>(x, off1_w, wqc1, conv1_b, wqo, wq2,
                                     conv2_b, fc_w, fc_b, out);
}